// Round 4
// baseline (496.965 us; speedup 1.0000x reference)
//
#include <hip/hip_runtime.h>

typedef unsigned short u16;
typedef unsigned long long u64;
typedef __attribute__((ext_vector_type(8))) short short8;
typedef __attribute__((ext_vector_type(4))) float f32x4;

#define B_ 2048
#define D_ 512
#define CB_ 2048
#define K_ 200
#define NITEM_ 100001

__device__ __forceinline__ u16 f2bf_rne(float f) {
    unsigned u = __float_as_uint(f);
    unsigned r = (u + 0x7fffu + ((u >> 16) & 1u)) >> 16;
    return (u16)r;
}

__device__ __forceinline__ u64 shfl_xor_u64(u64 v, int m) {
    int lo = __shfl_xor((int)(v & 0xffffffffu), m);
    int hi = __shfl_xor((int)(v >> 32), m);
    return ((u64)(unsigned)hi << 32) | (unsigned)lo;
}

// ================= FUSED PREP (one dispatch, role-split by blockIdx) =================
// blocks [0,2048)      : codebook fp32->bf16 + fp64 row norms (+ zero diffacc/ticket)
// blocks [2048,2560)   : transpose W1 [512][1024] -> W1T bf16 [1024][512]
// blocks [2560,3072)   : transpose W2 [1024][512] -> W2T bf16 [512][1024]
// blocks [3072,5120)   : pos/neg row gathers (independent of everything else)
// blocks [5120,7168)   : item_embed fp32 -> int8 per-row-scale table (grid-stride rows)
__global__ void prep_misc(const float* __restrict__ cb, u16* __restrict__ ch,
                          float* __restrict__ cnormf, float* __restrict__ diffacc,
                          unsigned* __restrict__ ticket,
                          const float* __restrict__ W1, u16* __restrict__ W1T,
                          const float* __restrict__ W2, u16* __restrict__ W2T,
                          const int* __restrict__ pos, const int* __restrict__ neg,
                          const float* __restrict__ ie,
                          float* __restrict__ out1, float* __restrict__ out2,
                          char* __restrict__ q8, float* __restrict__ scales) {
    __shared__ double red[256];
    __shared__ float tile[32][33];
    int b = blockIdx.x, t = threadIdx.x;  // 256 threads
    if (b < 2048) {
        // ---- codebook prep: one row per block, float2 per thread ----
        int j = b;
        float2 v = ((const float2*)(cb + (size_t)j * D_))[t];
        ushort2 o;
        o.x = f2bf_rne(v.x); o.y = f2bf_rne(v.y);
        ((ushort2*)(ch + (size_t)j * D_))[t] = o;
        red[t] = (double)v.x * v.x + (double)v.y * v.y;
        __syncthreads();
        for (int s = 128; s > 0; s >>= 1) {
            if (t < s) red[t] += red[t + s];
            __syncthreads();
        }
        if (t == 0) {
            cnormf[j] = (float)red[0];
            if (j == 0) { diffacc[0] = 0.0f; ticket[0] = 0u; }
        }
    } else if (b < 3072) {
        // ---- weight transposes, 32x32 tiles ----
        const float* W; u16* WT; int K, N, bx, by;
        if (b < 2560) { W = W1; WT = W1T; K = 512;  N = 1024; int i = b - 2048; bx = i & 31; by = i >> 5; }
        else          { W = W2; WT = W2T; K = 1024; N = 512;  int i = b - 2560; bx = i & 15; by = i >> 4; }
        int n0 = bx * 32, k0 = by * 32;
        int kl = t >> 3, nl = (t & 7) * 4;
        float4 v = *(const float4*)(W + (size_t)(k0 + kl) * N + n0 + nl);
        tile[kl][nl] = v.x; tile[kl][nl + 1] = v.y; tile[kl][nl + 2] = v.z; tile[kl][nl + 3] = v.w;
        __syncthreads();
        int nl2 = t >> 3, kl2 = (t & 7) * 4;
        ushort4 o;
        o.x = f2bf_rne(tile[kl2][nl2]);
        o.y = f2bf_rne(tile[kl2 + 1][nl2]);
        o.z = f2bf_rne(tile[kl2 + 2][nl2]);
        o.w = f2bf_rne(tile[kl2 + 3][nl2]);
        *(ushort4*)(WT + (size_t)(n0 + nl2) * K + k0 + kl2) = o;
    } else if (b < 5120) {
        // ---- pos/neg gathers: block bb, threads 0-127 pos row, 128-255 neg row ----
        int bb = b - 3072;
        if (t < 128) {
            int p = pos[bb];
            ((float4*)(out1 + (size_t)bb * D_))[t] = ((const float4*)(ie + (size_t)p * D_))[t];
        } else {
            int n = neg[bb];
            int t2 = t - 128;
            ((float4*)(out2 + (size_t)bb * D_))[t2] = ((const float4*)(ie + (size_t)n * D_))[t2];
        }
    } else {
        // ---- item_embed fp32 -> int8 per-row scale; one wave per row, grid-stride ----
        int gw = (b - 5120) * 4 + (t >> 6);
        int lane = t & 63;
        for (int row = gw; row < NITEM_; row += 8192) {
            const float* rp = ie + (size_t)row * D_ + lane * 8;
            float4 a = *(const float4*)rp;
            float4 bb4 = *(const float4*)(rp + 4);
            float m = fmaxf(fmaxf(fmaxf(fabsf(a.x), fabsf(a.y)), fmaxf(fabsf(a.z), fabsf(a.w))),
                            fmaxf(fmaxf(fabsf(bb4.x), fabsf(bb4.y)), fmaxf(fabsf(bb4.z), fabsf(bb4.w))));
#pragma unroll
            for (int off = 32; off >= 1; off >>= 1)
                m = fmaxf(m, __shfl_xor(m, off));
            float inv = (m > 0.f) ? 127.0f / m : 0.f;
            float s = m * (1.0f / 127.0f);
            int q0 = __float2int_rn(a.x * inv) & 255;
            int q1 = __float2int_rn(a.y * inv) & 255;
            int q2 = __float2int_rn(a.z * inv) & 255;
            int q3 = __float2int_rn(a.w * inv) & 255;
            int q4 = __float2int_rn(bb4.x * inv) & 255;
            int q5 = __float2int_rn(bb4.y * inv) & 255;
            int q6 = __float2int_rn(bb4.z * inv) & 255;
            int q7 = __float2int_rn(bb4.w * inv) & 255;
            uint2 o;
            o.x = (unsigned)(q0 | (q1 << 8) | (q2 << 16) | (q3 << 24));
            o.y = (unsigned)(q4 | (q5 << 8) | (q6 << 16) | (q7 << 24));
            *(uint2*)(q8 + (size_t)row * D_ + lane * 8) = o;
            if (lane == 0) scales[row] = s;
        }
    }
}

// ---------------- standalone fallback pieces (small-ws path) ----------------
__global__ void cbprep_kernel(const float* __restrict__ cb, u16* __restrict__ ch,
                              float* __restrict__ cnormf, float* __restrict__ diffacc,
                              unsigned* __restrict__ ticket) {
    __shared__ double red[128];
    int j = blockIdx.x, t = threadIdx.x;
    float4 v = ((const float4*)(cb + (size_t)j * D_))[t];
    ushort4 o;
    o.x = f2bf_rne(v.x); o.y = f2bf_rne(v.y); o.z = f2bf_rne(v.z); o.w = f2bf_rne(v.w);
    ((ushort4*)(ch + (size_t)j * D_))[t] = o;
    red[t] = (double)v.x * v.x + (double)v.y * v.y + (double)v.z * v.z + (double)v.w * v.w;
    __syncthreads();
    for (int s = 64; s > 0; s >>= 1) {
        if (t < s) red[t] += red[t + s];
        __syncthreads();
    }
    if (t == 0) {
        cnormf[j] = (float)red[0];
        if (j == 0) { diffacc[0] = 0.0f; ticket[0] = 0u; }
    }
}

__global__ void transpose_w(const float* __restrict__ W, u16* __restrict__ WT, int K, int N) {
    __shared__ float tile[32][33];
    int n0 = blockIdx.x * 32, k0 = blockIdx.y * 32;
    int t = threadIdx.x;
    int kl = t >> 3, nl = (t & 7) * 4;
    float4 v = *(const float4*)(W + (size_t)(k0 + kl) * N + n0 + nl);
    tile[kl][nl] = v.x; tile[kl][nl + 1] = v.y; tile[kl][nl + 2] = v.z; tile[kl][nl + 3] = v.w;
    __syncthreads();
    int nl2 = t >> 3, kl2 = (t & 7) * 4;
    ushort4 o;
    o.x = f2bf_rne(tile[kl2][nl2]);
    o.y = f2bf_rne(tile[kl2 + 1][nl2]);
    o.z = f2bf_rne(tile[kl2 + 2][nl2]);
    o.w = f2bf_rne(tile[kl2 + 3][nl2]);
    *(ushort4*)(WT + (size_t)(n0 + nl2) * K + k0 + kl2) = o;
}

__global__ void gather_pn(const int* __restrict__ pos, const int* __restrict__ neg,
                          const float* __restrict__ ie,
                          float* __restrict__ out1, float* __restrict__ out2) {
    int b = blockIdx.x, t = threadIdx.x;  // 128 threads
    int p = pos[b], n = neg[b];
    ((float4*)(out1 + (size_t)b * 512))[t] = ((const float4*)(ie + (size_t)p * 512))[t];
    ((float4*)(out2 + (size_t)b * 512))[t] = ((const float4*)(ie + (size_t)n * 512))[t];
}

__global__ void mean_kernel_f32(const int* __restrict__ items,
                                const float* __restrict__ item_embed,
                                u16* __restrict__ meanb) {
    __shared__ int sidx[K_];
    __shared__ float4 rs4[128];
    __shared__ int rc;
    int b = blockIdx.x, t = threadIdx.x;   // 256 threads
    for (int k = t; k < K_; k += 256) sidx[k] = items[b * K_ + k];
    __syncthreads();
    int team = t >> 7;
    int lt = t & 127;
    int c = lt * 4;
    float s0 = 0.f, s1 = 0.f, s2 = 0.f, s3 = 0.f;
    int cnt = 0;
    int k0 = team * (K_ / 2);
#pragma unroll 4
    for (int k = k0; k < k0 + K_ / 2; k++) {
        int idx = sidx[k];
        float m = (idx != 0) ? 1.0f : 0.0f;
        cnt += (idx != 0) ? 1 : 0;
        float4 v = *(const float4*)(item_embed + (size_t)idx * D_ + c);
        s0 += v.x * m; s1 += v.y * m; s2 += v.z * m; s3 += v.w * m;
    }
    if (team == 1) {
        float4 p; p.x = s0; p.y = s1; p.z = s2; p.w = s3;
        rs4[lt] = p;
        if (lt == 0) rc = cnt;
    }
    __syncthreads();
    if (team == 0) {
        float4 p = rs4[lt];
        s0 += p.x; s1 += p.y; s2 += p.z; s3 += p.w;
        cnt += rc;
        float inv = 1.0f / (float)cnt;
        ushort4 o;
        o.x = f2bf_rne(s0 * inv); o.y = f2bf_rne(s1 * inv);
        o.z = f2bf_rne(s2 * inv); o.w = f2bf_rne(s3 * inv);
        *(ushort4*)(meanb + (size_t)b * D_ + c) = o;
    }
}

// ---------------- masked mean over history, int8 table path ----------------
__global__ void mean_kernel_q8(const int* __restrict__ items,
                               const char* __restrict__ q8,
                               const float* __restrict__ scales,
                               u16* __restrict__ meanb) {
    __shared__ int sidx[K_];
    __shared__ float rs[3][64][8];
    __shared__ int rn_[4];
    int b = blockIdx.x, t = threadIdx.x;   // 256 threads
    for (int k = t; k < K_; k += 256) sidx[k] = items[b * K_ + k];
    __syncthreads();
    int team = t >> 6;
    int lt = t & 63;
    float s[8] = {0.f, 0.f, 0.f, 0.f, 0.f, 0.f, 0.f, 0.f};
    int n0 = 0;
    int k0 = team * (K_ / 4);
#pragma unroll 4
    for (int k = k0; k < k0 + K_ / 4; k++) {
        int idx = sidx[k];
        n0 += (idx == 0) ? 1 : 0;
        float sc = scales[idx];
        uint2 qv = *(const uint2*)(q8 + (size_t)idx * D_ + lt * 8);
        unsigned dx = qv.x, dy = qv.y;
        s[0] += (float)((int)(dx << 24) >> 24) * sc;
        s[1] += (float)((int)(dx << 16) >> 24) * sc;
        s[2] += (float)((int)(dx <<  8) >> 24) * sc;
        s[3] += (float)((int)dx >> 24) * sc;
        s[4] += (float)((int)(dy << 24) >> 24) * sc;
        s[5] += (float)((int)(dy << 16) >> 24) * sc;
        s[6] += (float)((int)(dy <<  8) >> 24) * sc;
        s[7] += (float)((int)dy >> 24) * sc;
    }
    if (team > 0) {
#pragma unroll
        for (int e = 0; e < 8; e++) rs[team - 1][lt][e] = s[e];
    }
    if (lt == 0) rn_[team] = n0;
    __syncthreads();
    if (team == 0) {
#pragma unroll
        for (int tm = 0; tm < 3; tm++)
#pragma unroll
            for (int e = 0; e < 8; e++) s[e] += rs[tm][lt][e];
        int n0t = rn_[0] + rn_[1] + rn_[2] + rn_[3];
        float inv = 1.0f / (float)(K_ - n0t);
        float fn0 = (float)n0t;
        float s0 = scales[0];
        uint2 q0 = *(const uint2*)(q8 + lt * 8);
        unsigned dx = q0.x, dy = q0.y;
        float r0[8];
        r0[0] = (float)((int)(dx << 24) >> 24) * s0;
        r0[1] = (float)((int)(dx << 16) >> 24) * s0;
        r0[2] = (float)((int)(dx <<  8) >> 24) * s0;
        r0[3] = (float)((int)dx >> 24) * s0;
        r0[4] = (float)((int)(dy << 24) >> 24) * s0;
        r0[5] = (float)((int)(dy << 16) >> 24) * s0;
        r0[6] = (float)((int)(dy <<  8) >> 24) * s0;
        r0[7] = (float)((int)dy >> 24) * s0;
        short8 o;
#pragma unroll
        for (int e = 0; e < 8; e++)
            o[e] = (short)f2bf_rne((s[e] - fn0 * r0[e]) * inv);
        *(short8*)(meanb + (size_t)b * D_ + lt * 8) = o;
    }
}

// ---------------- GEMM1 (MFMA): h = relu(mean @ W1 + b1) -> hb bf16 [2048][1024] ----------------
__global__ void gemm1_mfma(const u16* __restrict__ meanb, const u16* __restrict__ W1T,
                           const float* __restrict__ b1w, u16* __restrict__ hb) {
    int t = threadIdx.x;
    int wid = blockIdx.x * 4 + (t >> 6);
    int lane = t & 63;
    int mt = wid >> 5, nt = wid & 31;
    int m0 = mt * 16, n0 = nt * 32;
    int mr = lane & 15, quad = lane >> 4, kb = quad * 8;
    const u16* ap  = meanb + (size_t)(m0 + mr) * 512 + kb;
    const u16* bp0 = W1T + (size_t)(n0 + mr) * 512 + kb;
    const u16* bp1 = bp0 + 16 * 512;
    f32x4 acc0 = {0.f, 0.f, 0.f, 0.f}, acc1 = {0.f, 0.f, 0.f, 0.f};
#pragma unroll
    for (int ks = 0; ks < 16; ks++) {
        short8 a  = *(const short8*)(ap  + ks * 32);
        short8 b0 = *(const short8*)(bp0 + ks * 32);
        short8 b1 = *(const short8*)(bp1 + ks * 32);
        acc0 = __builtin_amdgcn_mfma_f32_16x16x32_bf16(a, b0, acc0, 0, 0, 0);
        acc1 = __builtin_amdgcn_mfma_f32_16x16x32_bf16(a, b1, acc1, 0, 0, 0);
    }
    float bias0 = b1w[n0 + mr], bias1 = b1w[n0 + 16 + mr];
#pragma unroll
    for (int r = 0; r < 4; r++) {
        int m = m0 + quad * 4 + r;
        float v0 = acc0[r] + bias0; v0 = v0 > 0.f ? v0 : 0.f;
        float v1 = acc1[r] + bias1; v1 = v1 > 0.f ? v1 : 0.f;
        hb[(size_t)m * 1024 + n0 + mr]      = f2bf_rne(v0);
        hb[(size_t)m * 1024 + n0 + 16 + mr] = f2bf_rne(v1);
    }
}

// ---------------- GEMM2 (MFMA): u = h @ W2 + b2 -> out4 fp32 + uh bf16 ----------------
__global__ void gemm2_mfma(const u16* __restrict__ hb, const u16* __restrict__ W2T,
                           const float* __restrict__ b2w,
                           float* __restrict__ out_ue, u16* __restrict__ uh) {
    int t = threadIdx.x;
    int wid = blockIdx.x * 4 + (t >> 6);
    int lane = t & 63;
    int mt = wid >> 5, nt = wid & 31;
    int m0 = mt * 16, n0 = nt * 16;
    int mr = lane & 15, quad = lane >> 4, kb = quad * 8;
    const u16* ap = hb  + (size_t)(m0 + mr) * 1024 + kb;
    const u16* bp = W2T + (size_t)(n0 + mr) * 1024 + kb;
    f32x4 acc0 = {0.f, 0.f, 0.f, 0.f}, acc1 = {0.f, 0.f, 0.f, 0.f};
#pragma unroll
    for (int ks = 0; ks < 16; ks++) {
        short8 a0 = *(const short8*)(ap + ks * 32);
        short8 b0 = *(const short8*)(bp + ks * 32);
        short8 a1 = *(const short8*)(ap + 512 + ks * 32);
        short8 b1 = *(const short8*)(bp + 512 + ks * 32);
        acc0 = __builtin_amdgcn_mfma_f32_16x16x32_bf16(a0, b0, acc0, 0, 0, 0);
        acc1 = __builtin_amdgcn_mfma_f32_16x16x32_bf16(a1, b1, acc1, 0, 0, 0);
    }
    float bias = b2w[n0 + mr];
#pragma unroll
    for (int r = 0; r < 4; r++) {
        int m = m0 + quad * 4 + r;
        float v = acc0[r] + acc1[r] + bias;
        size_t o = (size_t)m * 512 + n0 + mr;
        out_ue[o] = v;
        uh[o] = f2bf_rne(v);
    }
}

// ---------------- VQ score (MFMA) ----------------
__global__ void score_mfma(const u16* __restrict__ uh,
                           const u16* __restrict__ ch,
                           const float* __restrict__ cnormf,
                           u64* __restrict__ pminS) {
    __shared__ u64 red2[64];
    int t = threadIdx.x, lane = t & 63, w = t >> 6;
    int ustrip = blockIdx.x >> 3, jstrip = blockIdx.x & 7;
    int u0 = ustrip * 16;
    int j0 = jstrip * 256 + w * 64;
    int mr = lane & 15, quad = lane >> 4, kb = quad * 8;

    short8 af[16];
    const u16* ap = uh + (size_t)(u0 + mr) * 512 + kb;
#pragma unroll
    for (int ks = 0; ks < 16; ks++) af[ks] = *(const short8*)(ap + ks * 32);

    u64 best[4] = {~0ull, ~0ull, ~0ull, ~0ull};
    for (int jt = 0; jt < 4; jt++) {
        int jb = j0 + jt * 16;
        const u16* bp = ch + (size_t)(jb + mr) * 512 + kb;
        f32x4 acc = {0.f, 0.f, 0.f, 0.f};
#pragma unroll
        for (int ks = 0; ks < 16; ks++) {
            short8 bv = *(const short8*)(bp + ks * 32);
            acc = __builtin_amdgcn_mfma_f32_16x16x32_bf16(af[ks], bv, acc, 0, 0, 0);
        }
        int n = jb + mr;
        float cn = cnormf[n];
#pragma unroll
        for (int r = 0; r < 4; r++) {
            float d2 = cn - 2.0f * acc[r];
            u64 p = (((u64)__float_as_uint(d2)) << 32) | (unsigned)n;
            if (p < best[r]) best[r] = p;
        }
    }
#pragma unroll
    for (int off = 8; off >= 1; off >>= 1)
#pragma unroll
        for (int r = 0; r < 4; r++) {
            u64 o = shfl_xor_u64(best[r], off);
            if (o < best[r]) best[r] = o;
        }
    if (mr == 0) {
#pragma unroll
        for (int r = 0; r < 4; r++) red2[w * 16 + quad * 4 + r] = best[r];
    }
    __syncthreads();
    if (t < 16) {
        u64 m = red2[t];
#pragma unroll
        for (int ww = 1; ww < 4; ww++) {
            u64 v = red2[ww * 16 + t];
            if (v < m) m = v;
        }
        pminS[(size_t)(u0 + t) * 8 + jstrip] = m;
    }
}

// ---------------- straight-through output + commitment loss + fused diff scalar ----------------
__global__ void finalize_user(const u64* __restrict__ pminS,
                              const float* __restrict__ ub,
                              const float* __restrict__ cb,
                              float* __restrict__ out0,
                              float* __restrict__ diffacc,
                              unsigned* __restrict__ ticket,
                              float* __restrict__ out3) {
    __shared__ u64 sm64[8];
    __shared__ unsigned sbest;
    __shared__ float red[256];
    int b = blockIdx.x, t = threadIdx.x;
    if (t < 8) sm64[t] = pminS[(size_t)b * 8 + t];
    __syncthreads();
    if (t == 0) {
        u64 m = sm64[0];
#pragma unroll
        for (int i = 1; i < 8; i++) if (sm64[i] < m) m = sm64[i];
        sbest = (unsigned)(m & 0xffffffffu);
    }
    __syncthreads();
    unsigned bestj = sbest;
    int c = t * 2;
    float2 qv = ((const float2*)(cb + (size_t)bestj * 512))[t];
    float w0 = ub[(size_t)b * 512 + c];
    float w1 = ub[(size_t)b * 512 + c + 1];
    float2 o;
    o.x = w0 + (qv.x - w0);
    o.y = w1 + (qv.y - w1);
    ((float2*)(out0 + (size_t)b * 512))[t] = o;
    float d0 = qv.x - w0, d1 = qv.y - w1;
    red[t] = d0 * d0 + d1 * d1;
    __syncthreads();
    for (int s = 128; s > 0; s >>= 1) {
        if (t < s) red[t] += red[t + s];
        __syncthreads();
    }
    if (t == 0) {
        atomicAdd(diffacc, red[0]);
        __threadfence();
        unsigned my = atomicAdd(ticket, 1u);
        if (my == (unsigned)(B_ - 1)) {
            __threadfence();
            float total = atomicAdd(diffacc, 0.0f);   // all adds visible: each preceded its ticket inc via fence
            out3[0] = total * (1.0f / ((float)B_ * (float)D_));
        }
    }
}

extern "C" void kernel_launch(void* const* d_in, const int* in_sizes, int n_in,
                              void* d_out, int out_size, void* d_ws, size_t ws_size,
                              hipStream_t stream) {
    const int* items = (const int*)d_in[1];
    const int* pos   = (const int*)d_in[2];
    const int* neg   = (const int*)d_in[3];
    const float* item_embed = (const float*)d_in[4];
    const float* W1 = (const float*)d_in[5];
    const float* b1 = (const float*)d_in[6];
    const float* W2 = (const float*)d_in[7];
    const float* b2 = (const float*)d_in[8];
    const float* cb = (const float*)d_in[9];

    float* out0 = (float*)d_out;             // quant_user [B,D]
    float* out1 = out0 + (size_t)B_ * D_;    // pos_item
    float* out2 = out1 + (size_t)B_ * D_;    // neg_item
    float* out3 = out2 + (size_t)B_ * D_;    // diff scalar
    float* out4 = out3 + 1;                  // user_embed [B,D]

    // workspace layout (fused path needs 64.45 MB; ws is ~819 MB per fill counter):
    char* wsb = (char*)d_ws;
    u16* meanb = (u16*)wsb;                          // 2 MB   [0, 2M)
    u16* W1T   = (u16*)(wsb + 2097152);              // 1 MB
    u16* W2T   = (u16*)(wsb + 3145728);              // 1 MB
    u16* uh    = (u16*)(wsb + 4194304);              // 2 MB
    u16* ch    = (u16*)(wsb + 6291456);              // 2 MB
    u64* pminS = (u64*)(wsb + 8388608);              // 128 KB
    float* cnormf   = (float*)(wsb + 8519680);       // 8 KB
    float* diffacc  = (float*)(wsb + 8527872);       // 4 B
    unsigned* ticket = (unsigned*)(wsb + 8527876);   // 4 B
    u16* hbw   = (u16*)(wsb + 8650752);              // 4 MB  bf16 h [2048][1024]
    char*  iq8  = (char*)(wsb + 12845056);           // 51.2 MB int8 item table
    float* iscal = (float*)(wsb + 64045568);         // 400 KB per-row scales
    const size_t WS_NEED_FULL = 64445572ull;
    const bool fused = (ws_size >= WS_NEED_FULL);

    if (fused) {
        // 6 dispatches total
        prep_misc<<<dim3(7168), dim3(256), 0, stream>>>(
            cb, ch, cnormf, diffacc, ticket, W1, W1T, W2, W2T,
            pos, neg, item_embed, out1, out2, iq8, iscal);
        mean_kernel_q8<<<dim3(B_), dim3(256), 0, stream>>>(items, iq8, iscal, meanb);
        gemm1_mfma<<<dim3(1024), dim3(256), 0, stream>>>(meanb, W1T, b1, hbw);
        gemm2_mfma<<<dim3(1024), dim3(256), 0, stream>>>(hbw, W2T, b2, out4, uh);
        score_mfma<<<dim3(1024), dim3(256), 0, stream>>>(uh, ch, cnormf, pminS);
        finalize_user<<<dim3(B_), dim3(256), 0, stream>>>(pminS, out4, cb, out0, diffacc, ticket, out3);
    } else {
        // fallback: hb aliases out1 (bf16 [2048][1024] = 4 MB), gather_pn last
        u16* hb = (u16*)out1;
        cbprep_kernel<<<dim3(CB_), dim3(128), 0, stream>>>(cb, ch, cnormf, diffacc, ticket);
        transpose_w<<<dim3(32, 16), dim3(256), 0, stream>>>(W1, W1T, 512, 1024);
        transpose_w<<<dim3(16, 32), dim3(256), 0, stream>>>(W2, W2T, 1024, 512);
        mean_kernel_f32<<<dim3(B_), dim3(256), 0, stream>>>(items, item_embed, meanb);
        gemm1_mfma<<<dim3(1024), dim3(256), 0, stream>>>(meanb, W1T, b1, hb);
        gemm2_mfma<<<dim3(1024), dim3(256), 0, stream>>>(hb, W2T, b2, out4, uh);
        score_mfma<<<dim3(1024), dim3(256), 0, stream>>>(uh, ch, cnormf, pminS);
        finalize_user<<<dim3(B_), dim3(256), 0, stream>>>(pminS, out4, cb, out0, diffacc, ticket, out3);
        gather_pn<<<dim3(B_), dim3(128), 0, stream>>>(pos, neg, item_embed, out1, out2);
    }
}

// Round 5
// 496.643 us; speedup vs baseline: 1.0006x; 1.0006x over previous
//
#include <hip/hip_runtime.h>

typedef unsigned short u16;
typedef unsigned long long u64;
typedef __attribute__((ext_vector_type(8))) short short8;
typedef __attribute__((ext_vector_type(4))) float f32x4;

#define B_ 2048
#define D_ 512
#define CB_ 2048
#define K_ 200
#define NITEM_ 100001

__device__ __forceinline__ u16 f2bf_rne(float f) {
    unsigned u = __float_as_uint(f);
    unsigned r = (u + 0x7fffu + ((u >> 16) & 1u)) >> 16;
    return (u16)r;
}

__device__ __forceinline__ u64 shfl_xor_u64(u64 v, int m) {
    int lo = __shfl_xor((int)(v & 0xffffffffu), m);
    int hi = __shfl_xor((int)(v >> 32), m);
    return ((u64)(unsigned)hi << 32) | (unsigned)lo;
}

// ================= FUSED SMALL PREP (one dispatch, short balanced roles only) =================
// blocks [0,2048)      : codebook fp32->bf16 + fp64 row norms (+ zero diffacc/ticket)
// blocks [2048,2560)   : transpose W1 [512][1024] -> W1T bf16 [1024][512]
// blocks [2560,3072)   : transpose W2 [1024][512] -> W2T bf16 [512][1024]
// blocks [3072,5120)   : pos/neg row gathers
// (ie2q8 deliberately NOT fused: round-4 evidence shows the long-pole role at the
//  tail of a mega-grid regresses ~20 us; it runs standalone right after.)
__global__ void prep_small(const float* __restrict__ cb, u16* __restrict__ ch,
                           float* __restrict__ cnormf, float* __restrict__ diffacc,
                           unsigned* __restrict__ ticket,
                           const float* __restrict__ W1, u16* __restrict__ W1T,
                           const float* __restrict__ W2, u16* __restrict__ W2T,
                           const int* __restrict__ pos, const int* __restrict__ neg,
                           const float* __restrict__ ie,
                           float* __restrict__ out1, float* __restrict__ out2) {
    __shared__ double red[256];
    __shared__ float tile[32][33];
    int b = blockIdx.x, t = threadIdx.x;  // 256 threads
    if (b < 2048) {
        // ---- codebook prep: one row per block, float2 per thread ----
        int j = b;
        float2 v = ((const float2*)(cb + (size_t)j * D_))[t];
        ushort2 o;
        o.x = f2bf_rne(v.x); o.y = f2bf_rne(v.y);
        ((ushort2*)(ch + (size_t)j * D_))[t] = o;
        red[t] = (double)v.x * v.x + (double)v.y * v.y;
        __syncthreads();
        for (int s = 128; s > 0; s >>= 1) {
            if (t < s) red[t] += red[t + s];
            __syncthreads();
        }
        if (t == 0) {
            cnormf[j] = (float)red[0];
            if (j == 0) { diffacc[0] = 0.0f; ticket[0] = 0u; }
        }
    } else if (b < 3072) {
        // ---- weight transposes, 32x32 tiles ----
        const float* W; u16* WT; int K, N, bx, by;
        if (b < 2560) { W = W1; WT = W1T; K = 512;  N = 1024; int i = b - 2048; bx = i & 31; by = i >> 5; }
        else          { W = W2; WT = W2T; K = 1024; N = 512;  int i = b - 2560; bx = i & 15; by = i >> 4; }
        int n0 = bx * 32, k0 = by * 32;
        int kl = t >> 3, nl = (t & 7) * 4;
        float4 v = *(const float4*)(W + (size_t)(k0 + kl) * N + n0 + nl);
        tile[kl][nl] = v.x; tile[kl][nl + 1] = v.y; tile[kl][nl + 2] = v.z; tile[kl][nl + 3] = v.w;
        __syncthreads();
        int nl2 = t >> 3, kl2 = (t & 7) * 4;
        ushort4 o;
        o.x = f2bf_rne(tile[kl2][nl2]);
        o.y = f2bf_rne(tile[kl2 + 1][nl2]);
        o.z = f2bf_rne(tile[kl2 + 2][nl2]);
        o.w = f2bf_rne(tile[kl2 + 3][nl2]);
        *(ushort4*)(WT + (size_t)(n0 + nl2) * K + k0 + kl2) = o;
    } else {
        // ---- pos/neg gathers: block bb, threads 0-127 pos row, 128-255 neg row ----
        int bb = b - 3072;
        if (t < 128) {
            int p = pos[bb];
            ((float4*)(out1 + (size_t)bb * D_))[t] = ((const float4*)(ie + (size_t)p * D_))[t];
        } else {
            int n = neg[bb];
            int t2 = t - 128;
            ((float4*)(out2 + (size_t)bb * D_))[t2] = ((const float4*)(ie + (size_t)n * D_))[t2];
        }
    }
}

// ---------------- item_embed fp32 -> int8 per-row-scale table (standalone, round-3 form) ----------------
__global__ void ie2q8_kernel(const float* __restrict__ ie, char* __restrict__ q8,
                             float* __restrict__ scales) {
    int gw = (blockIdx.x * 256 + threadIdx.x) >> 6;   // global wave id
    int lane = threadIdx.x & 63;
    int nw = (gridDim.x * 256) >> 6;
    for (int row = gw; row < NITEM_; row += nw) {
        const float* rp = ie + (size_t)row * D_ + lane * 8;
        float4 a = *(const float4*)rp;
        float4 b = *(const float4*)(rp + 4);
        float m = fmaxf(fmaxf(fmaxf(fabsf(a.x), fabsf(a.y)), fmaxf(fabsf(a.z), fabsf(a.w))),
                        fmaxf(fmaxf(fabsf(b.x), fabsf(b.y)), fmaxf(fabsf(b.z), fabsf(b.w))));
#pragma unroll
        for (int off = 32; off >= 1; off >>= 1)
            m = fmaxf(m, __shfl_xor(m, off));
        float inv = (m > 0.f) ? 127.0f / m : 0.f;
        float s = m * (1.0f / 127.0f);
        int q0 = __float2int_rn(a.x * inv) & 255;
        int q1 = __float2int_rn(a.y * inv) & 255;
        int q2 = __float2int_rn(a.z * inv) & 255;
        int q3 = __float2int_rn(a.w * inv) & 255;
        int q4 = __float2int_rn(b.x * inv) & 255;
        int q5 = __float2int_rn(b.y * inv) & 255;
        int q6 = __float2int_rn(b.z * inv) & 255;
        int q7 = __float2int_rn(b.w * inv) & 255;
        uint2 o;
        o.x = (unsigned)(q0 | (q1 << 8) | (q2 << 16) | (q3 << 24));
        o.y = (unsigned)(q4 | (q5 << 8) | (q6 << 16) | (q7 << 24));
        *(uint2*)(q8 + (size_t)row * D_ + lane * 8) = o;
        if (lane == 0) scales[row] = s;
    }
}

// ---------------- standalone fallback pieces (small-ws path) ----------------
__global__ void cbprep_kernel(const float* __restrict__ cb, u16* __restrict__ ch,
                              float* __restrict__ cnormf, float* __restrict__ diffacc,
                              unsigned* __restrict__ ticket) {
    __shared__ double red[128];
    int j = blockIdx.x, t = threadIdx.x;
    float4 v = ((const float4*)(cb + (size_t)j * D_))[t];
    ushort4 o;
    o.x = f2bf_rne(v.x); o.y = f2bf_rne(v.y); o.z = f2bf_rne(v.z); o.w = f2bf_rne(v.w);
    ((ushort4*)(ch + (size_t)j * D_))[t] = o;
    red[t] = (double)v.x * v.x + (double)v.y * v.y + (double)v.z * v.z + (double)v.w * v.w;
    __syncthreads();
    for (int s = 64; s > 0; s >>= 1) {
        if (t < s) red[t] += red[t + s];
        __syncthreads();
    }
    if (t == 0) {
        cnormf[j] = (float)red[0];
        if (j == 0) { diffacc[0] = 0.0f; ticket[0] = 0u; }
    }
}

__global__ void transpose_w(const float* __restrict__ W, u16* __restrict__ WT, int K, int N) {
    __shared__ float tile[32][33];
    int n0 = blockIdx.x * 32, k0 = blockIdx.y * 32;
    int t = threadIdx.x;
    int kl = t >> 3, nl = (t & 7) * 4;
    float4 v = *(const float4*)(W + (size_t)(k0 + kl) * N + n0 + nl);
    tile[kl][nl] = v.x; tile[kl][nl + 1] = v.y; tile[kl][nl + 2] = v.z; tile[kl][nl + 3] = v.w;
    __syncthreads();
    int nl2 = t >> 3, kl2 = (t & 7) * 4;
    ushort4 o;
    o.x = f2bf_rne(tile[kl2][nl2]);
    o.y = f2bf_rne(tile[kl2 + 1][nl2]);
    o.z = f2bf_rne(tile[kl2 + 2][nl2]);
    o.w = f2bf_rne(tile[kl2 + 3][nl2]);
    *(ushort4*)(WT + (size_t)(n0 + nl2) * K + k0 + kl2) = o;
}

__global__ void gather_pn(const int* __restrict__ pos, const int* __restrict__ neg,
                          const float* __restrict__ ie,
                          float* __restrict__ out1, float* __restrict__ out2) {
    int b = blockIdx.x, t = threadIdx.x;  // 128 threads
    int p = pos[b], n = neg[b];
    ((float4*)(out1 + (size_t)b * 512))[t] = ((const float4*)(ie + (size_t)p * 512))[t];
    ((float4*)(out2 + (size_t)b * 512))[t] = ((const float4*)(ie + (size_t)n * 512))[t];
}

__global__ void mean_kernel_f32(const int* __restrict__ items,
                                const float* __restrict__ item_embed,
                                u16* __restrict__ meanb) {
    __shared__ int sidx[K_];
    __shared__ float4 rs4[128];
    __shared__ int rc;
    int b = blockIdx.x, t = threadIdx.x;   // 256 threads
    for (int k = t; k < K_; k += 256) sidx[k] = items[b * K_ + k];
    __syncthreads();
    int team = t >> 7;
    int lt = t & 127;
    int c = lt * 4;
    float s0 = 0.f, s1 = 0.f, s2 = 0.f, s3 = 0.f;
    int cnt = 0;
    int k0 = team * (K_ / 2);
#pragma unroll 4
    for (int k = k0; k < k0 + K_ / 2; k++) {
        int idx = sidx[k];
        float m = (idx != 0) ? 1.0f : 0.0f;
        cnt += (idx != 0) ? 1 : 0;
        float4 v = *(const float4*)(item_embed + (size_t)idx * D_ + c);
        s0 += v.x * m; s1 += v.y * m; s2 += v.z * m; s3 += v.w * m;
    }
    if (team == 1) {
        float4 p; p.x = s0; p.y = s1; p.z = s2; p.w = s3;
        rs4[lt] = p;
        if (lt == 0) rc = cnt;
    }
    __syncthreads();
    if (team == 0) {
        float4 p = rs4[lt];
        s0 += p.x; s1 += p.y; s2 += p.z; s3 += p.w;
        cnt += rc;
        float inv = 1.0f / (float)cnt;
        ushort4 o;
        o.x = f2bf_rne(s0 * inv); o.y = f2bf_rne(s1 * inv);
        o.z = f2bf_rne(s2 * inv); o.w = f2bf_rne(s3 * inv);
        *(ushort4*)(meanb + (size_t)b * D_ + c) = o;
    }
}

// ---------------- masked mean over history, int8 table path (round-3 form) ----------------
__global__ void mean_kernel_q8(const int* __restrict__ items,
                               const char* __restrict__ q8,
                               const float* __restrict__ scales,
                               u16* __restrict__ meanb) {
    __shared__ int sidx[K_];
    __shared__ float rs[3][64][8];
    __shared__ int rn_[4];
    int b = blockIdx.x, t = threadIdx.x;   // 256 threads
    for (int k = t; k < K_; k += 256) sidx[k] = items[b * K_ + k];
    __syncthreads();
    int team = t >> 6;
    int lt = t & 63;
    float s[8] = {0.f, 0.f, 0.f, 0.f, 0.f, 0.f, 0.f, 0.f};
    int n0 = 0;
    int k0 = team * (K_ / 4);
#pragma unroll 4
    for (int k = k0; k < k0 + K_ / 4; k++) {
        int idx = sidx[k];
        n0 += (idx == 0) ? 1 : 0;
        float sc = scales[idx];
        uint2 qv = *(const uint2*)(q8 + (size_t)idx * D_ + lt * 8);
        unsigned dx = qv.x, dy = qv.y;
        s[0] += (float)((int)(dx << 24) >> 24) * sc;
        s[1] += (float)((int)(dx << 16) >> 24) * sc;
        s[2] += (float)((int)(dx <<  8) >> 24) * sc;
        s[3] += (float)((int)dx >> 24) * sc;
        s[4] += (float)((int)(dy << 24) >> 24) * sc;
        s[5] += (float)((int)(dy << 16) >> 24) * sc;
        s[6] += (float)((int)(dy <<  8) >> 24) * sc;
        s[7] += (float)((int)dy >> 24) * sc;
    }
    if (team > 0) {
#pragma unroll
        for (int e = 0; e < 8; e++) rs[team - 1][lt][e] = s[e];
    }
    if (lt == 0) rn_[team] = n0;
    __syncthreads();
    if (team == 0) {
#pragma unroll
        for (int tm = 0; tm < 3; tm++)
#pragma unroll
            for (int e = 0; e < 8; e++) s[e] += rs[tm][lt][e];
        int n0t = rn_[0] + rn_[1] + rn_[2] + rn_[3];
        float inv = 1.0f / (float)(K_ - n0t);
        float fn0 = (float)n0t;
        float s0 = scales[0];
        uint2 q0 = *(const uint2*)(q8 + lt * 8);
        unsigned dx = q0.x, dy = q0.y;
        float r0[8];
        r0[0] = (float)((int)(dx << 24) >> 24) * s0;
        r0[1] = (float)((int)(dx << 16) >> 24) * s0;
        r0[2] = (float)((int)(dx <<  8) >> 24) * s0;
        r0[3] = (float)((int)dx >> 24) * s0;
        r0[4] = (float)((int)(dy << 24) >> 24) * s0;
        r0[5] = (float)((int)(dy << 16) >> 24) * s0;
        r0[6] = (float)((int)(dy <<  8) >> 24) * s0;
        r0[7] = (float)((int)dy >> 24) * s0;
        short8 o;
#pragma unroll
        for (int e = 0; e < 8; e++)
            o[e] = (short)f2bf_rne((s[e] - fn0 * r0[e]) * inv);
        *(short8*)(meanb + (size_t)b * D_ + lt * 8) = o;
    }
}

// ---------------- GEMM1 (MFMA): h = relu(mean @ W1 + b1) -> hb bf16 [2048][1024] ----------------
__global__ void gemm1_mfma(const u16* __restrict__ meanb, const u16* __restrict__ W1T,
                           const float* __restrict__ b1w, u16* __restrict__ hb) {
    int t = threadIdx.x;
    int wid = blockIdx.x * 4 + (t >> 6);
    int lane = t & 63;
    int mt = wid >> 5, nt = wid & 31;
    int m0 = mt * 16, n0 = nt * 32;
    int mr = lane & 15, quad = lane >> 4, kb = quad * 8;
    const u16* ap  = meanb + (size_t)(m0 + mr) * 512 + kb;
    const u16* bp0 = W1T + (size_t)(n0 + mr) * 512 + kb;
    const u16* bp1 = bp0 + 16 * 512;
    f32x4 acc0 = {0.f, 0.f, 0.f, 0.f}, acc1 = {0.f, 0.f, 0.f, 0.f};
#pragma unroll
    for (int ks = 0; ks < 16; ks++) {
        short8 a  = *(const short8*)(ap  + ks * 32);
        short8 b0 = *(const short8*)(bp0 + ks * 32);
        short8 b1 = *(const short8*)(bp1 + ks * 32);
        acc0 = __builtin_amdgcn_mfma_f32_16x16x32_bf16(a, b0, acc0, 0, 0, 0);
        acc1 = __builtin_amdgcn_mfma_f32_16x16x32_bf16(a, b1, acc1, 0, 0, 0);
    }
    float bias0 = b1w[n0 + mr], bias1 = b1w[n0 + 16 + mr];
#pragma unroll
    for (int r = 0; r < 4; r++) {
        int m = m0 + quad * 4 + r;
        float v0 = acc0[r] + bias0; v0 = v0 > 0.f ? v0 : 0.f;
        float v1 = acc1[r] + bias1; v1 = v1 > 0.f ? v1 : 0.f;
        hb[(size_t)m * 1024 + n0 + mr]      = f2bf_rne(v0);
        hb[(size_t)m * 1024 + n0 + 16 + mr] = f2bf_rne(v1);
    }
}

// ---------------- GEMM2 (MFMA): u = h @ W2 + b2 -> out4 fp32 + uh bf16 ----------------
__global__ void gemm2_mfma(const u16* __restrict__ hb, const u16* __restrict__ W2T,
                           const float* __restrict__ b2w,
                           float* __restrict__ out_ue, u16* __restrict__ uh) {
    int t = threadIdx.x;
    int wid = blockIdx.x * 4 + (t >> 6);
    int lane = t & 63;
    int mt = wid >> 5, nt = wid & 31;
    int m0 = mt * 16, n0 = nt * 16;
    int mr = lane & 15, quad = lane >> 4, kb = quad * 8;
    const u16* ap = hb  + (size_t)(m0 + mr) * 1024 + kb;
    const u16* bp = W2T + (size_t)(n0 + mr) * 1024 + kb;
    f32x4 acc0 = {0.f, 0.f, 0.f, 0.f}, acc1 = {0.f, 0.f, 0.f, 0.f};
#pragma unroll
    for (int ks = 0; ks < 16; ks++) {
        short8 a0 = *(const short8*)(ap + ks * 32);
        short8 b0 = *(const short8*)(bp + ks * 32);
        short8 a1 = *(const short8*)(ap + 512 + ks * 32);
        short8 b1 = *(const short8*)(bp + 512 + ks * 32);
        acc0 = __builtin_amdgcn_mfma_f32_16x16x32_bf16(a0, b0, acc0, 0, 0, 0);
        acc1 = __builtin_amdgcn_mfma_f32_16x16x32_bf16(a1, b1, acc1, 0, 0, 0);
    }
    float bias = b2w[n0 + mr];
#pragma unroll
    for (int r = 0; r < 4; r++) {
        int m = m0 + quad * 4 + r;
        float v = acc0[r] + acc1[r] + bias;
        size_t o = (size_t)m * 512 + n0 + mr;
        out_ue[o] = v;
        uh[o] = f2bf_rne(v);
    }
}

// ---------------- VQ score (MFMA) ----------------
__global__ void score_mfma(const u16* __restrict__ uh,
                           const u16* __restrict__ ch,
                           const float* __restrict__ cnormf,
                           u64* __restrict__ pminS) {
    __shared__ u64 red2[64];
    int t = threadIdx.x, lane = t & 63, w = t >> 6;
    int ustrip = blockIdx.x >> 3, jstrip = blockIdx.x & 7;
    int u0 = ustrip * 16;
    int j0 = jstrip * 256 + w * 64;
    int mr = lane & 15, quad = lane >> 4, kb = quad * 8;

    short8 af[16];
    const u16* ap = uh + (size_t)(u0 + mr) * 512 + kb;
#pragma unroll
    for (int ks = 0; ks < 16; ks++) af[ks] = *(const short8*)(ap + ks * 32);

    u64 best[4] = {~0ull, ~0ull, ~0ull, ~0ull};
    for (int jt = 0; jt < 4; jt++) {
        int jb = j0 + jt * 16;
        const u16* bp = ch + (size_t)(jb + mr) * 512 + kb;
        f32x4 acc = {0.f, 0.f, 0.f, 0.f};
#pragma unroll
        for (int ks = 0; ks < 16; ks++) {
            short8 bv = *(const short8*)(bp + ks * 32);
            acc = __builtin_amdgcn_mfma_f32_16x16x32_bf16(af[ks], bv, acc, 0, 0, 0);
        }
        int n = jb + mr;
        float cn = cnormf[n];
#pragma unroll
        for (int r = 0; r < 4; r++) {
            float d2 = cn - 2.0f * acc[r];
            u64 p = (((u64)__float_as_uint(d2)) << 32) | (unsigned)n;
            if (p < best[r]) best[r] = p;
        }
    }
#pragma unroll
    for (int off = 8; off >= 1; off >>= 1)
#pragma unroll
        for (int r = 0; r < 4; r++) {
            u64 o = shfl_xor_u64(best[r], off);
            if (o < best[r]) best[r] = o;
        }
    if (mr == 0) {
#pragma unroll
        for (int r = 0; r < 4; r++) red2[w * 16 + quad * 4 + r] = best[r];
    }
    __syncthreads();
    if (t < 16) {
        u64 m = red2[t];
#pragma unroll
        for (int ww = 1; ww < 4; ww++) {
            u64 v = red2[ww * 16 + t];
            if (v < m) m = v;
        }
        pminS[(size_t)(u0 + t) * 8 + jstrip] = m;
    }
}

// ---------------- straight-through output + commitment loss + fused diff scalar ----------------
__global__ void finalize_user(const u64* __restrict__ pminS,
                              const float* __restrict__ ub,
                              const float* __restrict__ cb,
                              float* __restrict__ out0,
                              float* __restrict__ diffacc,
                              unsigned* __restrict__ ticket,
                              float* __restrict__ out3) {
    __shared__ u64 sm64[8];
    __shared__ unsigned sbest;
    __shared__ float red[256];
    int b = blockIdx.x, t = threadIdx.x;
    if (t < 8) sm64[t] = pminS[(size_t)b * 8 + t];
    __syncthreads();
    if (t == 0) {
        u64 m = sm64[0];
#pragma unroll
        for (int i = 1; i < 8; i++) if (sm64[i] < m) m = sm64[i];
        sbest = (unsigned)(m & 0xffffffffu);
    }
    __syncthreads();
    unsigned bestj = sbest;
    int c = t * 2;
    float2 qv = ((const float2*)(cb + (size_t)bestj * 512))[t];
    float w0 = ub[(size_t)b * 512 + c];
    float w1 = ub[(size_t)b * 512 + c + 1];
    float2 o;
    o.x = w0 + (qv.x - w0);
    o.y = w1 + (qv.y - w1);
    ((float2*)(out0 + (size_t)b * 512))[t] = o;
    float d0 = qv.x - w0, d1 = qv.y - w1;
    red[t] = d0 * d0 + d1 * d1;
    __syncthreads();
    for (int s = 128; s > 0; s >>= 1) {
        if (t < s) red[t] += red[t + s];
        __syncthreads();
    }
    if (t == 0) {
        atomicAdd(diffacc, red[0]);
        __threadfence();
        unsigned my = atomicAdd(ticket, 1u);
        if (my == (unsigned)(B_ - 1)) {
            __threadfence();
            float total = atomicAdd(diffacc, 0.0f);
            out3[0] = total * (1.0f / ((float)B_ * (float)D_));
        }
    }
}

extern "C" void kernel_launch(void* const* d_in, const int* in_sizes, int n_in,
                              void* d_out, int out_size, void* d_ws, size_t ws_size,
                              hipStream_t stream) {
    const int* items = (const int*)d_in[1];
    const int* pos   = (const int*)d_in[2];
    const int* neg   = (const int*)d_in[3];
    const float* item_embed = (const float*)d_in[4];
    const float* W1 = (const float*)d_in[5];
    const float* b1 = (const float*)d_in[6];
    const float* W2 = (const float*)d_in[7];
    const float* b2 = (const float*)d_in[8];
    const float* cb = (const float*)d_in[9];

    float* out0 = (float*)d_out;             // quant_user [B,D]
    float* out1 = out0 + (size_t)B_ * D_;    // pos_item
    float* out2 = out1 + (size_t)B_ * D_;    // neg_item
    float* out3 = out2 + (size_t)B_ * D_;    // diff scalar
    float* out4 = out3 + 1;                  // user_embed [B,D]

    // workspace layout (full path needs 64.45 MB; ws ~819 MB per fill counter):
    char* wsb = (char*)d_ws;
    u16* meanb = (u16*)wsb;                          // 2 MB   [0, 2M)
    u16* W1T   = (u16*)(wsb + 2097152);              // 1 MB
    u16* W2T   = (u16*)(wsb + 3145728);              // 1 MB
    u16* uh    = (u16*)(wsb + 4194304);              // 2 MB
    u16* ch    = (u16*)(wsb + 6291456);              // 2 MB
    u64* pminS = (u64*)(wsb + 8388608);              // 128 KB
    float* cnormf   = (float*)(wsb + 8519680);       // 8 KB
    float* diffacc  = (float*)(wsb + 8527872);       // 4 B
    unsigned* ticket = (unsigned*)(wsb + 8527876);   // 4 B
    u16* hbw   = (u16*)(wsb + 8650752);              // 4 MB  bf16 h [2048][1024]
    char*  iq8  = (char*)(wsb + 12845056);           // 51.2 MB int8 item table
    float* iscal = (float*)(wsb + 64045568);         // 400 KB per-row scales
    const size_t WS_NEED_FULL = 64445572ull;
    const bool full = (ws_size >= WS_NEED_FULL);

    if (full) {
        // 7 dispatches
        prep_small<<<dim3(5120), dim3(256), 0, stream>>>(
            cb, ch, cnormf, diffacc, ticket, W1, W1T, W2, W2T,
            pos, neg, item_embed, out1, out2);
        ie2q8_kernel<<<dim3(2048), dim3(256), 0, stream>>>(item_embed, iq8, iscal);
        mean_kernel_q8<<<dim3(B_), dim3(256), 0, stream>>>(items, iq8, iscal, meanb);
        gemm1_mfma<<<dim3(1024), dim3(256), 0, stream>>>(meanb, W1T, b1, hbw);
        gemm2_mfma<<<dim3(1024), dim3(256), 0, stream>>>(hbw, W2T, b2, out4, uh);
        score_mfma<<<dim3(1024), dim3(256), 0, stream>>>(uh, ch, cnormf, pminS);
        finalize_user<<<dim3(B_), dim3(256), 0, stream>>>(pminS, out4, cb, out0, diffacc, ticket, out3);
    } else {
        // fallback: hb aliases out1 (bf16 [2048][1024] = 4 MB), gather_pn last
        u16* hb = (u16*)out1;
        cbprep_kernel<<<dim3(CB_), dim3(128), 0, stream>>>(cb, ch, cnormf, diffacc, ticket);
        transpose_w<<<dim3(32, 16), dim3(256), 0, stream>>>(W1, W1T, 512, 1024);
        transpose_w<<<dim3(16, 32), dim3(256), 0, stream>>>(W2, W2T, 1024, 512);
        mean_kernel_f32<<<dim3(B_), dim3(256), 0, stream>>>(items, item_embed, meanb);
        gemm1_mfma<<<dim3(1024), dim3(256), 0, stream>>>(meanb, W1T, b1, hb);
        gemm2_mfma<<<dim3(1024), dim3(256), 0, stream>>>(hb, W2T, b2, out4, uh);
        score_mfma<<<dim3(1024), dim3(256), 0, stream>>>(uh, ch, cnormf, pminS);
        finalize_user<<<dim3(B_), dim3(256), 0, stream>>>(pminS, out4, cb, out0, diffacc, ticket, out3);
        gather_pn<<<dim3(B_), dim3(128), 0, stream>>>(pos, neg, item_embed, out1, out2);
    }
}

// Round 6
// 478.228 us; speedup vs baseline: 1.0392x; 1.0385x over previous
//
#include <hip/hip_runtime.h>

typedef unsigned short u16;
typedef unsigned long long u64;
typedef __attribute__((ext_vector_type(8))) short short8;
typedef __attribute__((ext_vector_type(4))) float f32x4;

#define B_ 2048
#define D_ 512
#define CB_ 2048
#define K_ 200
#define NITEM_ 100001

__device__ __forceinline__ u16 f2bf_rne(float f) {
    unsigned u = __float_as_uint(f);
    unsigned r = (u + 0x7fffu + ((u >> 16) & 1u)) >> 16;
    return (u16)r;
}

__device__ __forceinline__ u64 shfl_xor_u64(u64 v, int m) {
    int lo = __shfl_xor((int)(v & 0xffffffffu), m);
    int hi = __shfl_xor((int)(v >> 32), m);
    return ((u64)(unsigned)hi << 32) | (unsigned)lo;
}

// ---------------- prep: cb fp32 -> bf16 rows + fp64-exact row norms + diffacc=0 ----------------
// grid CB_ blocks x 128 thr; block j handles one codebook row
__global__ void cbprep_kernel(const float* __restrict__ cb, u16* __restrict__ ch,
                              float* __restrict__ cnormf, float* __restrict__ diffacc) {
    __shared__ double red[128];
    int j = blockIdx.x, t = threadIdx.x;
    float4 v = ((const float4*)(cb + (size_t)j * D_))[t];
    ushort4 o;
    o.x = f2bf_rne(v.x); o.y = f2bf_rne(v.y); o.z = f2bf_rne(v.z); o.w = f2bf_rne(v.w);
    ((ushort4*)(ch + (size_t)j * D_))[t] = o;
    red[t] = (double)v.x * v.x + (double)v.y * v.y + (double)v.z * v.z + (double)v.w * v.w;
    __syncthreads();
    for (int s = 64; s > 0; s >>= 1) {
        if (t < s) red[t] += red[t + s];
        __syncthreads();
    }
    if (t == 0) {
        cnormf[j] = (float)red[0];
        if (j == 0) diffacc[0] = 0.0f;
    }
}

// ---------------- W [K][N] fp32 -> WT [N][K] bf16, 32x32 tiles ----------------
__global__ void transpose_w(const float* __restrict__ W, u16* __restrict__ WT, int K, int N) {
    __shared__ float tile[32][33];
    int n0 = blockIdx.x * 32, k0 = blockIdx.y * 32;
    int t = threadIdx.x;
    int kl = t >> 3, nl = (t & 7) * 4;
    float4 v = *(const float4*)(W + (size_t)(k0 + kl) * N + n0 + nl);
    tile[kl][nl] = v.x; tile[kl][nl + 1] = v.y; tile[kl][nl + 2] = v.z; tile[kl][nl + 3] = v.w;
    __syncthreads();
    int nl2 = t >> 3, kl2 = (t & 7) * 4;
    ushort4 o;
    o.x = f2bf_rne(tile[kl2][nl2]);
    o.y = f2bf_rne(tile[kl2 + 1][nl2]);
    o.z = f2bf_rne(tile[kl2 + 2][nl2]);
    o.w = f2bf_rne(tile[kl2 + 3][nl2]);
    *(ushort4*)(WT + (size_t)(n0 + nl2) * K + k0 + kl2) = o;
}

// ---------------- item_embed fp32 -> int8 per-row-scale table ----------------
// one wave per row, grid-stride; lane covers 8 consecutive floats (2x float4 read, uint2 write)
__global__ void ie2q8_kernel(const float* __restrict__ ie, char* __restrict__ q8,
                             float* __restrict__ scales) {
    int gw = (blockIdx.x * 256 + threadIdx.x) >> 6;   // global wave id
    int lane = threadIdx.x & 63;
    int nw = (gridDim.x * 256) >> 6;
    for (int row = gw; row < NITEM_; row += nw) {
        const float* rp = ie + (size_t)row * D_ + lane * 8;
        float4 a = *(const float4*)rp;
        float4 b = *(const float4*)(rp + 4);
        float m = fmaxf(fmaxf(fmaxf(fabsf(a.x), fabsf(a.y)), fmaxf(fabsf(a.z), fabsf(a.w))),
                        fmaxf(fmaxf(fabsf(b.x), fabsf(b.y)), fmaxf(fabsf(b.z), fabsf(b.w))));
#pragma unroll
        for (int off = 32; off >= 1; off >>= 1)
            m = fmaxf(m, __shfl_xor(m, off));
        float inv = (m > 0.f) ? 127.0f / m : 0.f;
        float s = m * (1.0f / 127.0f);
        int q0 = __float2int_rn(a.x * inv) & 255;
        int q1 = __float2int_rn(a.y * inv) & 255;
        int q2 = __float2int_rn(a.z * inv) & 255;
        int q3 = __float2int_rn(a.w * inv) & 255;
        int q4 = __float2int_rn(b.x * inv) & 255;
        int q5 = __float2int_rn(b.y * inv) & 255;
        int q6 = __float2int_rn(b.z * inv) & 255;
        int q7 = __float2int_rn(b.w * inv) & 255;
        uint2 o;
        o.x = (unsigned)(q0 | (q1 << 8) | (q2 << 16) | (q3 << 24));
        o.y = (unsigned)(q4 | (q5 << 8) | (q6 << 16) | (q7 << 24));
        *(uint2*)(q8 + (size_t)row * D_ + lane * 8) = o;
        if (lane == 0) scales[row] = s;
    }
}

// ---------------- masked mean over history, int8 table path ----------------
// 256 thr = 4 waves; each wave handles 50 items; 64 lanes x 8 int8 = one 512-elem row.
// PAD trick: always load (PAD aliases row 0), count n0, subtract n0*row0 at the end
// (row 0 decoded identically in both places -> exact cancellation to fp32 rounding).
__global__ void mean_kernel_q8(const int* __restrict__ items,
                               const char* __restrict__ q8,
                               const float* __restrict__ scales,
                               u16* __restrict__ meanb) {
    __shared__ int sidx[K_];
    __shared__ float rs[3][64][8];
    __shared__ int rn_[4];
    int b = blockIdx.x, t = threadIdx.x;   // 256 threads
    for (int k = t; k < K_; k += 256) sidx[k] = items[b * K_ + k];
    __syncthreads();
    int team = t >> 6;
    int lt = t & 63;
    float s[8] = {0.f, 0.f, 0.f, 0.f, 0.f, 0.f, 0.f, 0.f};
    int n0 = 0;
    int k0 = team * (K_ / 4);
#pragma unroll 4
    for (int k = k0; k < k0 + K_ / 4; k++) {
        int idx = sidx[k];
        n0 += (idx == 0) ? 1 : 0;
        float sc = scales[idx];
        uint2 qv = *(const uint2*)(q8 + (size_t)idx * D_ + lt * 8);
        unsigned dx = qv.x, dy = qv.y;
        s[0] += (float)((int)(dx << 24) >> 24) * sc;
        s[1] += (float)((int)(dx << 16) >> 24) * sc;
        s[2] += (float)((int)(dx <<  8) >> 24) * sc;
        s[3] += (float)((int)dx >> 24) * sc;
        s[4] += (float)((int)(dy << 24) >> 24) * sc;
        s[5] += (float)((int)(dy << 16) >> 24) * sc;
        s[6] += (float)((int)(dy <<  8) >> 24) * sc;
        s[7] += (float)((int)dy >> 24) * sc;
    }
    if (team > 0) {
#pragma unroll
        for (int e = 0; e < 8; e++) rs[team - 1][lt][e] = s[e];
    }
    if (lt == 0) rn_[team] = n0;
    __syncthreads();
    if (team == 0) {
#pragma unroll
        for (int tm = 0; tm < 3; tm++)
#pragma unroll
            for (int e = 0; e < 8; e++) s[e] += rs[tm][lt][e];
        int n0t = rn_[0] + rn_[1] + rn_[2] + rn_[3];
        float inv = 1.0f / (float)(K_ - n0t);
        float fn0 = (float)n0t;
        float s0 = scales[0];
        uint2 q0 = *(const uint2*)(q8 + lt * 8);
        unsigned dx = q0.x, dy = q0.y;
        float r0[8];
        r0[0] = (float)((int)(dx << 24) >> 24) * s0;
        r0[1] = (float)((int)(dx << 16) >> 24) * s0;
        r0[2] = (float)((int)(dx <<  8) >> 24) * s0;
        r0[3] = (float)((int)dx >> 24) * s0;
        r0[4] = (float)((int)(dy << 24) >> 24) * s0;
        r0[5] = (float)((int)(dy << 16) >> 24) * s0;
        r0[6] = (float)((int)(dy <<  8) >> 24) * s0;
        r0[7] = (float)((int)dy >> 24) * s0;
        short8 o;
#pragma unroll
        for (int e = 0; e < 8; e++)
            o[e] = (short)f2bf_rne((s[e] - fn0 * r0[e]) * inv);
        *(short8*)(meanb + (size_t)b * D_ + lt * 8) = o;
    }
}

// ---------------- masked mean, fp32 fallback (if workspace too small for q8 table) ----------------
__global__ void mean_kernel_f32(const int* __restrict__ items,
                                const float* __restrict__ item_embed,
                                u16* __restrict__ meanb) {
    __shared__ int sidx[K_];
    __shared__ float4 rs4[128];
    __shared__ int rc;
    int b = blockIdx.x, t = threadIdx.x;   // 256 threads
    for (int k = t; k < K_; k += 256) sidx[k] = items[b * K_ + k];
    __syncthreads();
    int team = t >> 7;
    int lt = t & 127;
    int c = lt * 4;
    float s0 = 0.f, s1 = 0.f, s2 = 0.f, s3 = 0.f;
    int cnt = 0;
    int k0 = team * (K_ / 2);
#pragma unroll 4
    for (int k = k0; k < k0 + K_ / 2; k++) {
        int idx = sidx[k];
        float m = (idx != 0) ? 1.0f : 0.0f;
        cnt += (idx != 0) ? 1 : 0;
        float4 v = *(const float4*)(item_embed + (size_t)idx * D_ + c);
        s0 += v.x * m; s1 += v.y * m; s2 += v.z * m; s3 += v.w * m;
    }
    if (team == 1) {
        float4 p; p.x = s0; p.y = s1; p.z = s2; p.w = s3;
        rs4[lt] = p;
        if (lt == 0) rc = cnt;
    }
    __syncthreads();
    if (team == 0) {
        float4 p = rs4[lt];
        s0 += p.x; s1 += p.y; s2 += p.z; s3 += p.w;
        cnt += rc;
        float inv = 1.0f / (float)cnt;
        ushort4 o;
        o.x = f2bf_rne(s0 * inv); o.y = f2bf_rne(s1 * inv);
        o.z = f2bf_rne(s2 * inv); o.w = f2bf_rne(s3 * inv);
        *(ushort4*)(meanb + (size_t)b * D_ + c) = o;
    }
}

// ---------------- GEMM1 (MFMA): h = relu(mean @ W1 + b1) -> hb bf16 [2048][1024] ----------------
__global__ void gemm1_mfma(const u16* __restrict__ meanb, const u16* __restrict__ W1T,
                           const float* __restrict__ b1w, u16* __restrict__ hb) {
    int t = threadIdx.x;
    int wid = blockIdx.x * 4 + (t >> 6);
    int lane = t & 63;
    int mt = wid >> 5, nt = wid & 31;
    int m0 = mt * 16, n0 = nt * 32;
    int mr = lane & 15, quad = lane >> 4, kb = quad * 8;
    const u16* ap  = meanb + (size_t)(m0 + mr) * 512 + kb;
    const u16* bp0 = W1T + (size_t)(n0 + mr) * 512 + kb;
    const u16* bp1 = bp0 + 16 * 512;
    f32x4 acc0 = {0.f, 0.f, 0.f, 0.f}, acc1 = {0.f, 0.f, 0.f, 0.f};
#pragma unroll
    for (int ks = 0; ks < 16; ks++) {
        short8 a  = *(const short8*)(ap  + ks * 32);
        short8 b0 = *(const short8*)(bp0 + ks * 32);
        short8 b1 = *(const short8*)(bp1 + ks * 32);
        acc0 = __builtin_amdgcn_mfma_f32_16x16x32_bf16(a, b0, acc0, 0, 0, 0);
        acc1 = __builtin_amdgcn_mfma_f32_16x16x32_bf16(a, b1, acc1, 0, 0, 0);
    }
    float bias0 = b1w[n0 + mr], bias1 = b1w[n0 + 16 + mr];
#pragma unroll
    for (int r = 0; r < 4; r++) {
        int m = m0 + quad * 4 + r;
        float v0 = acc0[r] + bias0; v0 = v0 > 0.f ? v0 : 0.f;
        float v1 = acc1[r] + bias1; v1 = v1 > 0.f ? v1 : 0.f;
        hb[(size_t)m * 1024 + n0 + mr]      = f2bf_rne(v0);
        hb[(size_t)m * 1024 + n0 + 16 + mr] = f2bf_rne(v1);
    }
}

// ---------------- GEMM2 (MFMA): u = h @ W2 + b2 -> out4 fp32 + uh bf16 ----------------
__global__ void gemm2_mfma(const u16* __restrict__ hb, const u16* __restrict__ W2T,
                           const float* __restrict__ b2w,
                           float* __restrict__ out_ue, u16* __restrict__ uh) {
    int t = threadIdx.x;
    int wid = blockIdx.x * 4 + (t >> 6);
    int lane = t & 63;
    int mt = wid >> 5, nt = wid & 31;
    int m0 = mt * 16, n0 = nt * 16;
    int mr = lane & 15, quad = lane >> 4, kb = quad * 8;
    const u16* ap = hb  + (size_t)(m0 + mr) * 1024 + kb;
    const u16* bp = W2T + (size_t)(n0 + mr) * 1024 + kb;
    f32x4 acc0 = {0.f, 0.f, 0.f, 0.f}, acc1 = {0.f, 0.f, 0.f, 0.f};
#pragma unroll
    for (int ks = 0; ks < 16; ks++) {
        short8 a0 = *(const short8*)(ap + ks * 32);
        short8 b0 = *(const short8*)(bp + ks * 32);
        short8 a1 = *(const short8*)(ap + 512 + ks * 32);
        short8 b1 = *(const short8*)(bp + 512 + ks * 32);
        acc0 = __builtin_amdgcn_mfma_f32_16x16x32_bf16(a0, b0, acc0, 0, 0, 0);
        acc1 = __builtin_amdgcn_mfma_f32_16x16x32_bf16(a1, b1, acc1, 0, 0, 0);
    }
    float bias = b2w[n0 + mr];
#pragma unroll
    for (int r = 0; r < 4; r++) {
        int m = m0 + quad * 4 + r;
        float v = acc0[r] + acc1[r] + bias;
        size_t o = (size_t)m * 512 + n0 + mr;
        out_ue[o] = v;
        uh[o] = f2bf_rne(v);
    }
}

// ---------------- VQ score (MFMA): d2 = cnorm - 2*(U.C^T); block = 16 users x 256 j ----------------
__global__ void score_mfma(const u16* __restrict__ uh,
                           const u16* __restrict__ ch,
                           const float* __restrict__ cnormf,
                           u64* __restrict__ pminS) {
    __shared__ u64 red2[64];
    int t = threadIdx.x, lane = t & 63, w = t >> 6;
    int ustrip = blockIdx.x >> 3, jstrip = blockIdx.x & 7;
    int u0 = ustrip * 16;
    int j0 = jstrip * 256 + w * 64;
    int mr = lane & 15, quad = lane >> 4, kb = quad * 8;

    short8 af[16];
    const u16* ap = uh + (size_t)(u0 + mr) * 512 + kb;
#pragma unroll
    for (int ks = 0; ks < 16; ks++) af[ks] = *(const short8*)(ap + ks * 32);

    u64 best[4] = {~0ull, ~0ull, ~0ull, ~0ull};
    for (int jt = 0; jt < 4; jt++) {
        int jb = j0 + jt * 16;
        const u16* bp = ch + (size_t)(jb + mr) * 512 + kb;
        f32x4 acc = {0.f, 0.f, 0.f, 0.f};
#pragma unroll
        for (int ks = 0; ks < 16; ks++) {
            short8 bv = *(const short8*)(bp + ks * 32);
            acc = __builtin_amdgcn_mfma_f32_16x16x32_bf16(af[ks], bv, acc, 0, 0, 0);
        }
        int n = jb + mr;
        float cn = cnormf[n];
#pragma unroll
        for (int r = 0; r < 4; r++) {
            float d2 = cn - 2.0f * acc[r];
            u64 p = (((u64)__float_as_uint(d2)) << 32) | (unsigned)n;
            if (p < best[r]) best[r] = p;
        }
    }
#pragma unroll
    for (int off = 8; off >= 1; off >>= 1)
#pragma unroll
        for (int r = 0; r < 4; r++) {
            u64 o = shfl_xor_u64(best[r], off);
            if (o < best[r]) best[r] = o;
        }
    if (mr == 0) {
#pragma unroll
        for (int r = 0; r < 4; r++) red2[w * 16 + quad * 4 + r] = best[r];
    }
    __syncthreads();
    if (t < 16) {
        u64 m = red2[t];
#pragma unroll
        for (int ww = 1; ww < 4; ww++) {
            u64 v = red2[ww * 16 + t];
            if (v < m) m = v;
        }
        pminS[(size_t)(u0 + t) * 8 + jstrip] = m;
    }
}

// ---------------- straight-through output + commitment loss partials ----------------
__global__ void finalize_user(const u64* __restrict__ pminS,
                              const float* __restrict__ ub,
                              const float* __restrict__ cb,
                              float* __restrict__ out0,
                              float* __restrict__ diffacc) {
    __shared__ u64 sm64[8];
    __shared__ unsigned sbest;
    __shared__ float red[256];
    int b = blockIdx.x, t = threadIdx.x;
    if (t < 8) sm64[t] = pminS[(size_t)b * 8 + t];
    __syncthreads();
    if (t == 0) {
        u64 m = sm64[0];
#pragma unroll
        for (int i = 1; i < 8; i++) if (sm64[i] < m) m = sm64[i];
        sbest = (unsigned)(m & 0xffffffffu);
    }
    __syncthreads();
    unsigned bestj = sbest;
    int c = t * 2;
    float2 qv = ((const float2*)(cb + (size_t)bestj * 512))[t];
    float w0 = ub[(size_t)b * 512 + c];
    float w1 = ub[(size_t)b * 512 + c + 1];
    float2 o;
    o.x = w0 + (qv.x - w0);
    o.y = w1 + (qv.y - w1);
    ((float2*)(out0 + (size_t)b * 512))[t] = o;
    float d0 = qv.x - w0, d1 = qv.y - w1;
    red[t] = d0 * d0 + d1 * d1;
    __syncthreads();
    for (int s = 128; s > 0; s >>= 1) {
        if (t < s) red[t] += red[t + s];
        __syncthreads();
    }
    if (t == 0) atomicAdd(diffacc, red[0]);
}

// ---------------- pos/neg gathers (fp32 float4 copy) ----------------
__global__ void gather_pn(const int* __restrict__ pos, const int* __restrict__ neg,
                          const float* __restrict__ ie,
                          float* __restrict__ out1, float* __restrict__ out2) {
    int b = blockIdx.x, t = threadIdx.x;  // 128 threads
    int p = pos[b], n = neg[b];
    ((float4*)(out1 + (size_t)b * 512))[t] = ((const float4*)(ie + (size_t)p * 512))[t];
    ((float4*)(out2 + (size_t)b * 512))[t] = ((const float4*)(ie + (size_t)n * 512))[t];
}

// ---------------- diff scalar ----------------
__global__ void diff_final(const float* __restrict__ diffacc, float* __restrict__ out3) {
    if (threadIdx.x == 0)
        out3[0] = diffacc[0] * (1.0f / ((float)B_ * (float)D_));
}

extern "C" void kernel_launch(void* const* d_in, const int* in_sizes, int n_in,
                              void* d_out, int out_size, void* d_ws, size_t ws_size,
                              hipStream_t stream) {
    const int* items = (const int*)d_in[1];
    const int* pos   = (const int*)d_in[2];
    const int* neg   = (const int*)d_in[3];
    const float* item_embed = (const float*)d_in[4];
    const float* W1 = (const float*)d_in[5];
    const float* b1 = (const float*)d_in[6];
    const float* W2 = (const float*)d_in[7];
    const float* b2 = (const float*)d_in[8];
    const float* cb = (const float*)d_in[9];

    float* out0 = (float*)d_out;             // quant_user [B,D]
    float* out1 = out0 + (size_t)B_ * D_;    // pos_item — doubles as hb (bf16 [2048][1024] = 4 MB)
    float* out2 = out1 + (size_t)B_ * D_;    // neg_item
    float* out3 = out2 + (size_t)B_ * D_;    // diff scalar
    float* out4 = out3 + 1;                  // user_embed [B,D]

    u16* hb = (u16*)out1;                    // 4 MB bf16, overwritten by gather_pn at the end

    // workspace layout (round-3 proven config):
    char* wsb = (char*)d_ws;
    u16* meanb = (u16*)wsb;                          // 2 MB  [0, 2M)
    u16* W1T   = (u16*)(wsb + 2097152);              // 1 MB  [2M, 3M)
    u16* W2T   = (u16*)(wsb + 3145728);              // 1 MB  [3M, 4M)
    u16* uh    = (u16*)(wsb + 4194304);              // 2 MB  [4M, 6M)
    u16* ch    = (u16*)(wsb + 6291456);              // 2 MB  [6M, 8M)
    u64* pminS = (u64*)(wsb + 8388608);              // 128 KB
    float* cnormf  = (float*)(wsb + 8519680);        // 8 KB
    float* diffacc = (float*)(wsb + 8527872);        // 4 B
    char*  iq8     = (char*)(wsb + 8650752);         // 51.2 MB int8 item table
    float* iscal   = (float*)(wsb + 8650752 + 51200512);  // 400 KB per-row scales
    const size_t WS_NEED_Q8 = 8650752ull + 51200512ull + 400004ull;  // ~60.3 MB
    const bool use_q8 = (ws_size >= WS_NEED_Q8);

    cbprep_kernel<<<dim3(CB_), dim3(128), 0, stream>>>(cb, ch, cnormf, diffacc);
    transpose_w<<<dim3(32, 16), dim3(256), 0, stream>>>(W1, W1T, 512, 1024);
    transpose_w<<<dim3(16, 32), dim3(256), 0, stream>>>(W2, W2T, 1024, 512);
    if (use_q8) {
        ie2q8_kernel<<<dim3(2048), dim3(256), 0, stream>>>(item_embed, iq8, iscal);
        mean_kernel_q8<<<dim3(B_), dim3(256), 0, stream>>>(items, iq8, iscal, meanb);
    } else {
        mean_kernel_f32<<<dim3(B_), dim3(256), 0, stream>>>(items, item_embed, meanb);
    }
    gemm1_mfma<<<dim3(1024), dim3(256), 0, stream>>>(meanb, W1T, b1, hb);
    gemm2_mfma<<<dim3(1024), dim3(256), 0, stream>>>(hb, W2T, b2, out4, uh);
    score_mfma<<<dim3(1024), dim3(256), 0, stream>>>(uh, ch, cnormf, pminS);
    finalize_user<<<dim3(B_), dim3(256), 0, stream>>>(pminS, out4, cb, out0, diffacc);
    gather_pn<<<dim3(B_), dim3(128), 0, stream>>>(pos, neg, item_embed, out1, out2);
    diff_final<<<dim3(1), dim3(64), 0, stream>>>(diffacc, out3);
}

// Round 7
// 475.375 us; speedup vs baseline: 1.0454x; 1.0060x over previous
//
#include <hip/hip_runtime.h>

typedef unsigned short u16;
typedef unsigned long long u64;
typedef __attribute__((ext_vector_type(8))) short short8;
typedef __attribute__((ext_vector_type(4))) float f32x4;

#define B_ 2048
#define D_ 512
#define CB_ 2048
#define K_ 200
#define NITEM_ 100001

__device__ __forceinline__ u16 f2bf_rne(float f) {
    unsigned u = __float_as_uint(f);
    unsigned r = (u + 0x7fffu + ((u >> 16) & 1u)) >> 16;
    return (u16)r;
}

__device__ __forceinline__ u64 shfl_xor_u64(u64 v, int m) {
    int lo = __shfl_xor((int)(v & 0xffffffffu), m);
    int hi = __shfl_xor((int)(v >> 32), m);
    return ((u64)(unsigned)hi << 32) | (unsigned)lo;
}

// decode 16 signed int8 (one uint4) and accumulate into s[16]
__device__ __forceinline__ void dec16_acc(uint4 qv, float sc, float* s) {
    unsigned w[4] = {qv.x, qv.y, qv.z, qv.w};
#pragma unroll
    for (int j = 0; j < 4; j++) {
        s[4 * j + 0] += (float)((int)(w[j] << 24) >> 24) * sc;
        s[4 * j + 1] += (float)((int)(w[j] << 16) >> 24) * sc;
        s[4 * j + 2] += (float)((int)(w[j] <<  8) >> 24) * sc;
        s[4 * j + 3] += (float)((int)w[j] >> 24) * sc;
    }
}

// decode 16 signed int8 (one uint4) into r[16]
__device__ __forceinline__ void dec16_set(uint4 qv, float sc, float* r) {
    unsigned w[4] = {qv.x, qv.y, qv.z, qv.w};
#pragma unroll
    for (int j = 0; j < 4; j++) {
        r[4 * j + 0] = (float)((int)(w[j] << 24) >> 24) * sc;
        r[4 * j + 1] = (float)((int)(w[j] << 16) >> 24) * sc;
        r[4 * j + 2] = (float)((int)(w[j] <<  8) >> 24) * sc;
        r[4 * j + 3] = (float)((int)w[j] >> 24) * sc;
    }
}

// ---------------- prep: cb fp32 -> bf16 rows + fp64-exact row norms + diffacc=0 ----------------
__global__ void cbprep_kernel(const float* __restrict__ cb, u16* __restrict__ ch,
                              float* __restrict__ cnormf, float* __restrict__ diffacc) {
    __shared__ double red[128];
    int j = blockIdx.x, t = threadIdx.x;
    float4 v = ((const float4*)(cb + (size_t)j * D_))[t];
    ushort4 o;
    o.x = f2bf_rne(v.x); o.y = f2bf_rne(v.y); o.z = f2bf_rne(v.z); o.w = f2bf_rne(v.w);
    ((ushort4*)(ch + (size_t)j * D_))[t] = o;
    red[t] = (double)v.x * v.x + (double)v.y * v.y + (double)v.z * v.z + (double)v.w * v.w;
    __syncthreads();
    for (int s = 64; s > 0; s >>= 1) {
        if (t < s) red[t] += red[t + s];
        __syncthreads();
    }
    if (t == 0) {
        cnormf[j] = (float)red[0];
        if (j == 0) diffacc[0] = 0.0f;
    }
}

// ---------------- W [K][N] fp32 -> WT [N][K] bf16, 32x32 tiles ----------------
__global__ void transpose_w(const float* __restrict__ W, u16* __restrict__ WT, int K, int N) {
    __shared__ float tile[32][33];
    int n0 = blockIdx.x * 32, k0 = blockIdx.y * 32;
    int t = threadIdx.x;
    int kl = t >> 3, nl = (t & 7) * 4;
    float4 v = *(const float4*)(W + (size_t)(k0 + kl) * N + n0 + nl);
    tile[kl][nl] = v.x; tile[kl][nl + 1] = v.y; tile[kl][nl + 2] = v.z; tile[kl][nl + 3] = v.w;
    __syncthreads();
    int nl2 = t >> 3, kl2 = (t & 7) * 4;
    ushort4 o;
    o.x = f2bf_rne(tile[kl2][nl2]);
    o.y = f2bf_rne(tile[kl2 + 1][nl2]);
    o.z = f2bf_rne(tile[kl2 + 2][nl2]);
    o.w = f2bf_rne(tile[kl2 + 3][nl2]);
    *(ushort4*)(WT + (size_t)(n0 + nl2) * K + k0 + kl2) = o;
}

// ---------------- item_embed fp32 -> int8 per-row-scale table (2 rows/wave-iter, 16B lanes) ----------------
// wave: lanes 0-31 handle row base+0, lanes 32-63 row base+1; lane covers 16 consecutive els.
__global__ void ie2q8_kernel(const float* __restrict__ ie, char* __restrict__ q8,
                             float* __restrict__ scales) {
    int gw = (blockIdx.x * 256 + threadIdx.x) >> 6;   // global wave id
    int lane = threadIdx.x & 63;
    int half = lane >> 5, hl = lane & 31;
    int nw = (gridDim.x * 256) >> 6;
    for (int base = gw * 2; base < NITEM_; base += nw * 2) {
        int row = base + half;
        if (row >= NITEM_) row = NITEM_ - 1;   // dup of last row: same data, benign
        const float* rp = ie + (size_t)row * D_ + hl * 16;
        float4 a0 = *(const float4*)rp;
        float4 a1 = *(const float4*)(rp + 4);
        float4 a2 = *(const float4*)(rp + 8);
        float4 a3 = *(const float4*)(rp + 12);
        float f[16] = {a0.x, a0.y, a0.z, a0.w, a1.x, a1.y, a1.z, a1.w,
                       a2.x, a2.y, a2.z, a2.w, a3.x, a3.y, a3.z, a3.w};
        float m = 0.f;
#pragma unroll
        for (int e = 0; e < 16; e++) m = fmaxf(m, fabsf(f[e]));
#pragma unroll
        for (int off = 16; off >= 1; off >>= 1)      // reduce within the 32-lane half
            m = fmaxf(m, __shfl_xor(m, off));
        float inv = (m > 0.f) ? 127.0f / m : 0.f;
        float s = m * (1.0f / 127.0f);
        unsigned w[4];
#pragma unroll
        for (int j = 0; j < 4; j++) {
            int q0 = __float2int_rn(f[4 * j + 0] * inv) & 255;
            int q1 = __float2int_rn(f[4 * j + 1] * inv) & 255;
            int q2 = __float2int_rn(f[4 * j + 2] * inv) & 255;
            int q3 = __float2int_rn(f[4 * j + 3] * inv) & 255;
            w[j] = (unsigned)(q0 | (q1 << 8) | (q2 << 16) | (q3 << 24));
        }
        uint4 o; o.x = w[0]; o.y = w[1]; o.z = w[2]; o.w = w[3];
        *(uint4*)(q8 + (size_t)row * D_ + hl * 16) = o;
        if (hl == 0) scales[row] = s;
    }
}

// ---------------- masked mean over history, int8 table path (2 rows/wave-iter, 16B lanes) ----------------
// 256 thr = 4 waves; each wave: 50 items in 25 iters of 2 rows (half-wave per row).
// Lane covers 16 els; halves combined via shfl_xor(32); teams via LDS.
// PAD trick unchanged: always load (PAD aliases row 0), count n0, subtract n0*row0.
__global__ void mean_kernel_q8(const int* __restrict__ items,
                               const char* __restrict__ q8,
                               const float* __restrict__ scales,
                               u16* __restrict__ meanb) {
    __shared__ int sidx[K_];
    __shared__ float rs[3][32][16];
    __shared__ int rn_[4];
    int b = blockIdx.x, t = threadIdx.x;   // 256 threads
    for (int k = t; k < K_; k += 256) sidx[k] = items[b * K_ + k];
    __syncthreads();
    int team = t >> 6;        // wave id 0..3
    int lane = t & 63;
    int half = lane >> 5, hl = lane & 31;
    int co = hl * 16;         // element (= byte) offset within the 512-el row
    float s[16];
#pragma unroll
    for (int e = 0; e < 16; e++) s[e] = 0.f;
    int n0 = 0;
    int k0 = team * (K_ / 4);
#pragma unroll 5
    for (int i = 0; i < K_ / 8; i++) {    // 25 iterations, 2 items each
        int idx = sidx[k0 + 2 * i + half];
        n0 += (idx == 0) ? 1 : 0;
        float sc = scales[idx];
        uint4 qv = *(const uint4*)(q8 + (size_t)idx * D_ + co);
        dec16_acc(qv, sc, s);
    }
    // combine the two half-waves (rows interleaved between halves)
#pragma unroll
    for (int e = 0; e < 16; e++) s[e] += __shfl_xor(s[e], 32);
    n0 += __shfl_xor(n0, 32);
    if (team > 0 && half == 0) {
#pragma unroll
        for (int e = 0; e < 16; e++) rs[team - 1][hl][e] = s[e];
    }
    if (lane == 0) rn_[team] = n0;
    __syncthreads();
    if (team == 0 && half == 0) {
#pragma unroll
        for (int tm = 0; tm < 3; tm++)
#pragma unroll
            for (int e = 0; e < 16; e++) s[e] += rs[tm][hl][e];
        int n0t = rn_[0] + rn_[1] + rn_[2] + rn_[3];
        float inv = 1.0f / (float)(K_ - n0t);
        float fn0 = (float)n0t;
        float s0 = scales[0];
        uint4 q0 = *(const uint4*)(q8 + co);   // row 0 (the PAD row)
        float r0[16];
        dec16_set(q0, s0, r0);
        short8 o0, o1;
#pragma unroll
        for (int e = 0; e < 8; e++) {
            o0[e] = (short)f2bf_rne((s[e] - fn0 * r0[e]) * inv);
            o1[e] = (short)f2bf_rne((s[e + 8] - fn0 * r0[e + 8]) * inv);
        }
        *(short8*)(meanb + (size_t)b * D_ + co) = o0;
        *(short8*)(meanb + (size_t)b * D_ + co + 8) = o1;
    }
}

// ---------------- masked mean, fp32 fallback (if workspace too small for q8 table) ----------------
__global__ void mean_kernel_f32(const int* __restrict__ items,
                                const float* __restrict__ item_embed,
                                u16* __restrict__ meanb) {
    __shared__ int sidx[K_];
    __shared__ float4 rs4[128];
    __shared__ int rc;
    int b = blockIdx.x, t = threadIdx.x;   // 256 threads
    for (int k = t; k < K_; k += 256) sidx[k] = items[b * K_ + k];
    __syncthreads();
    int team = t >> 7;
    int lt = t & 127;
    int c = lt * 4;
    float s0 = 0.f, s1 = 0.f, s2 = 0.f, s3 = 0.f;
    int cnt = 0;
    int k0 = team * (K_ / 2);
#pragma unroll 4
    for (int k = k0; k < k0 + K_ / 2; k++) {
        int idx = sidx[k];
        float m = (idx != 0) ? 1.0f : 0.0f;
        cnt += (idx != 0) ? 1 : 0;
        float4 v = *(const float4*)(item_embed + (size_t)idx * D_ + c);
        s0 += v.x * m; s1 += v.y * m; s2 += v.z * m; s3 += v.w * m;
    }
    if (team == 1) {
        float4 p; p.x = s0; p.y = s1; p.z = s2; p.w = s3;
        rs4[lt] = p;
        if (lt == 0) rc = cnt;
    }
    __syncthreads();
    if (team == 0) {
        float4 p = rs4[lt];
        s0 += p.x; s1 += p.y; s2 += p.z; s3 += p.w;
        cnt += rc;
        float inv = 1.0f / (float)cnt;
        ushort4 o;
        o.x = f2bf_rne(s0 * inv); o.y = f2bf_rne(s1 * inv);
        o.z = f2bf_rne(s2 * inv); o.w = f2bf_rne(s3 * inv);
        *(ushort4*)(meanb + (size_t)b * D_ + c) = o;
    }
}

// ---------------- GEMM1 (MFMA): h = relu(mean @ W1 + b1) -> hb bf16 [2048][1024] ----------------
__global__ void gemm1_mfma(const u16* __restrict__ meanb, const u16* __restrict__ W1T,
                           const float* __restrict__ b1w, u16* __restrict__ hb) {
    int t = threadIdx.x;
    int wid = blockIdx.x * 4 + (t >> 6);
    int lane = t & 63;
    int mt = wid >> 5, nt = wid & 31;
    int m0 = mt * 16, n0 = nt * 32;
    int mr = lane & 15, quad = lane >> 4, kb = quad * 8;
    const u16* ap  = meanb + (size_t)(m0 + mr) * 512 + kb;
    const u16* bp0 = W1T + (size_t)(n0 + mr) * 512 + kb;
    const u16* bp1 = bp0 + 16 * 512;
    f32x4 acc0 = {0.f, 0.f, 0.f, 0.f}, acc1 = {0.f, 0.f, 0.f, 0.f};
#pragma unroll
    for (int ks = 0; ks < 16; ks++) {
        short8 a  = *(const short8*)(ap  + ks * 32);
        short8 b0 = *(const short8*)(bp0 + ks * 32);
        short8 b1 = *(const short8*)(bp1 + ks * 32);
        acc0 = __builtin_amdgcn_mfma_f32_16x16x32_bf16(a, b0, acc0, 0, 0, 0);
        acc1 = __builtin_amdgcn_mfma_f32_16x16x32_bf16(a, b1, acc1, 0, 0, 0);
    }
    float bias0 = b1w[n0 + mr], bias1 = b1w[n0 + 16 + mr];
#pragma unroll
    for (int r = 0; r < 4; r++) {
        int m = m0 + quad * 4 + r;
        float v0 = acc0[r] + bias0; v0 = v0 > 0.f ? v0 : 0.f;
        float v1 = acc1[r] + bias1; v1 = v1 > 0.f ? v1 : 0.f;
        hb[(size_t)m * 1024 + n0 + mr]      = f2bf_rne(v0);
        hb[(size_t)m * 1024 + n0 + 16 + mr] = f2bf_rne(v1);
    }
}

// ---------------- GEMM2 (MFMA): u = h @ W2 + b2 -> out4 fp32 + uh bf16 ----------------
__global__ void gemm2_mfma(const u16* __restrict__ hb, const u16* __restrict__ W2T,
                           const float* __restrict__ b2w,
                           float* __restrict__ out_ue, u16* __restrict__ uh) {
    int t = threadIdx.x;
    int wid = blockIdx.x * 4 + (t >> 6);
    int lane = t & 63;
    int mt = wid >> 5, nt = wid & 31;
    int m0 = mt * 16, n0 = nt * 16;
    int mr = lane & 15, quad = lane >> 4, kb = quad * 8;
    const u16* ap = hb  + (size_t)(m0 + mr) * 1024 + kb;
    const u16* bp = W2T + (size_t)(n0 + mr) * 1024 + kb;
    f32x4 acc0 = {0.f, 0.f, 0.f, 0.f}, acc1 = {0.f, 0.f, 0.f, 0.f};
#pragma unroll
    for (int ks = 0; ks < 16; ks++) {
        short8 a0 = *(const short8*)(ap + ks * 32);
        short8 b0 = *(const short8*)(bp + ks * 32);
        short8 a1 = *(const short8*)(ap + 512 + ks * 32);
        short8 b1 = *(const short8*)(bp + 512 + ks * 32);
        acc0 = __builtin_amdgcn_mfma_f32_16x16x32_bf16(a0, b0, acc0, 0, 0, 0);
        acc1 = __builtin_amdgcn_mfma_f32_16x16x32_bf16(a1, b1, acc1, 0, 0, 0);
    }
    float bias = b2w[n0 + mr];
#pragma unroll
    for (int r = 0; r < 4; r++) {
        int m = m0 + quad * 4 + r;
        float v = acc0[r] + acc1[r] + bias;
        size_t o = (size_t)m * 512 + n0 + mr;
        out_ue[o] = v;
        uh[o] = f2bf_rne(v);
    }
}

// ---------------- VQ score (MFMA): d2 = cnorm - 2*(U.C^T); block = 16 users x 256 j ----------------
__global__ void score_mfma(const u16* __restrict__ uh,
                           const u16* __restrict__ ch,
                           const float* __restrict__ cnormf,
                           u64* __restrict__ pminS) {
    __shared__ u64 red2[64];
    int t = threadIdx.x, lane = t & 63, w = t >> 6;
    int ustrip = blockIdx.x >> 3, jstrip = blockIdx.x & 7;
    int u0 = ustrip * 16;
    int j0 = jstrip * 256 + w * 64;
    int mr = lane & 15, quad = lane >> 4, kb = quad * 8;

    short8 af[16];
    const u16* ap = uh + (size_t)(u0 + mr) * 512 + kb;
#pragma unroll
    for (int ks = 0; ks < 16; ks++) af[ks] = *(const short8*)(ap + ks * 32);

    u64 best[4] = {~0ull, ~0ull, ~0ull, ~0ull};
    for (int jt = 0; jt < 4; jt++) {
        int jb = j0 + jt * 16;
        const u16* bp = ch + (size_t)(jb + mr) * 512 + kb;
        f32x4 acc = {0.f, 0.f, 0.f, 0.f};
#pragma unroll
        for (int ks = 0; ks < 16; ks++) {
            short8 bv = *(const short8*)(bp + ks * 32);
            acc = __builtin_amdgcn_mfma_f32_16x16x32_bf16(af[ks], bv, acc, 0, 0, 0);
        }
        int n = jb + mr;
        float cn = cnormf[n];
#pragma unroll
        for (int r = 0; r < 4; r++) {
            float d2 = cn - 2.0f * acc[r];
            u64 p = (((u64)__float_as_uint(d2)) << 32) | (unsigned)n;
            if (p < best[r]) best[r] = p;
        }
    }
#pragma unroll
    for (int off = 8; off >= 1; off >>= 1)
#pragma unroll
        for (int r = 0; r < 4; r++) {
            u64 o = shfl_xor_u64(best[r], off);
            if (o < best[r]) best[r] = o;
        }
    if (mr == 0) {
#pragma unroll
        for (int r = 0; r < 4; r++) red2[w * 16 + quad * 4 + r] = best[r];
    }
    __syncthreads();
    if (t < 16) {
        u64 m = red2[t];
#pragma unroll
        for (int ww = 1; ww < 4; ww++) {
            u64 v = red2[ww * 16 + t];
            if (v < m) m = v;
        }
        pminS[(size_t)(u0 + t) * 8 + jstrip] = m;
    }
}

// ---------------- straight-through output + commitment loss partials ----------------
__global__ void finalize_user(const u64* __restrict__ pminS,
                              const float* __restrict__ ub,
                              const float* __restrict__ cb,
                              float* __restrict__ out0,
                              float* __restrict__ diffacc) {
    __shared__ u64 sm64[8];
    __shared__ unsigned sbest;
    __shared__ float red[256];
    int b = blockIdx.x, t = threadIdx.x;
    if (t < 8) sm64[t] = pminS[(size_t)b * 8 + t];
    __syncthreads();
    if (t == 0) {
        u64 m = sm64[0];
#pragma unroll
        for (int i = 1; i < 8; i++) if (sm64[i] < m) m = sm64[i];
        sbest = (unsigned)(m & 0xffffffffu);
    }
    __syncthreads();
    unsigned bestj = sbest;
    int c = t * 2;
    float2 qv = ((const float2*)(cb + (size_t)bestj * 512))[t];
    float w0 = ub[(size_t)b * 512 + c];
    float w1 = ub[(size_t)b * 512 + c + 1];
    float2 o;
    o.x = w0 + (qv.x - w0);
    o.y = w1 + (qv.y - w1);
    ((float2*)(out0 + (size_t)b * 512))[t] = o;
    float d0 = qv.x - w0, d1 = qv.y - w1;
    red[t] = d0 * d0 + d1 * d1;
    __syncthreads();
    for (int s = 128; s > 0; s >>= 1) {
        if (t < s) red[t] += red[t + s];
        __syncthreads();
    }
    if (t == 0) atomicAdd(diffacc, red[0]);
}

// ---------------- pos/neg gathers (fp32 float4 copy) ----------------
__global__ void gather_pn(const int* __restrict__ pos, const int* __restrict__ neg,
                          const float* __restrict__ ie,
                          float* __restrict__ out1, float* __restrict__ out2) {
    int b = blockIdx.x, t = threadIdx.x;  // 128 threads
    int p = pos[b], n = neg[b];
    ((float4*)(out1 + (size_t)b * 512))[t] = ((const float4*)(ie + (size_t)p * 512))[t];
    ((float4*)(out2 + (size_t)b * 512))[t] = ((const float4*)(ie + (size_t)n * 512))[t];
}

// ---------------- diff scalar ----------------
__global__ void diff_final(const float* __restrict__ diffacc, float* __restrict__ out3) {
    if (threadIdx.x == 0)
        out3[0] = diffacc[0] * (1.0f / ((float)B_ * (float)D_));
}

extern "C" void kernel_launch(void* const* d_in, const int* in_sizes, int n_in,
                              void* d_out, int out_size, void* d_ws, size_t ws_size,
                              hipStream_t stream) {
    const int* items = (const int*)d_in[1];
    const int* pos   = (const int*)d_in[2];
    const int* neg   = (const int*)d_in[3];
    const float* item_embed = (const float*)d_in[4];
    const float* W1 = (const float*)d_in[5];
    const float* b1 = (const float*)d_in[6];
    const float* W2 = (const float*)d_in[7];
    const float* b2 = (const float*)d_in[8];
    const float* cb = (const float*)d_in[9];

    float* out0 = (float*)d_out;             // quant_user [B,D]
    float* out1 = out0 + (size_t)B_ * D_;    // pos_item — doubles as hb (bf16 [2048][1024] = 4 MB)
    float* out2 = out1 + (size_t)B_ * D_;    // neg_item
    float* out3 = out2 + (size_t)B_ * D_;    // diff scalar
    float* out4 = out3 + 1;                  // user_embed [B,D]

    u16* hb = (u16*)out1;                    // 4 MB bf16, overwritten by gather_pn at the end

    // workspace layout (round-3 proven config):
    char* wsb = (char*)d_ws;
    u16* meanb = (u16*)wsb;                          // 2 MB  [0, 2M)
    u16* W1T   = (u16*)(wsb + 2097152);              // 1 MB  [2M, 3M)
    u16* W2T   = (u16*)(wsb + 3145728);              // 1 MB  [3M, 4M)
    u16* uh    = (u16*)(wsb + 4194304);              // 2 MB  [4M, 6M)
    u16* ch    = (u16*)(wsb + 6291456);              // 2 MB  [6M, 8M)
    u64* pminS = (u64*)(wsb + 8388608);              // 128 KB
    float* cnormf  = (float*)(wsb + 8519680);        // 8 KB
    float* diffacc = (float*)(wsb + 8527872);        // 4 B
    char*  iq8     = (char*)(wsb + 8650752);         // 51.2 MB int8 item table
    float* iscal   = (float*)(wsb + 8650752 + 51200512);  // 400 KB per-row scales
    const size_t WS_NEED_Q8 = 8650752ull + 51200512ull + 400004ull;  // ~60.3 MB
    const bool use_q8 = (ws_size >= WS_NEED_Q8);

    cbprep_kernel<<<dim3(CB_), dim3(128), 0, stream>>>(cb, ch, cnormf, diffacc);
    transpose_w<<<dim3(32, 16), dim3(256), 0, stream>>>(W1, W1T, 512, 1024);
    transpose_w<<<dim3(16, 32), dim3(256), 0, stream>>>(W2, W2T, 1024, 512);
    if (use_q8) {
        ie2q8_kernel<<<dim3(2048), dim3(256), 0, stream>>>(item_embed, iq8, iscal);
        mean_kernel_q8<<<dim3(B_), dim3(256), 0, stream>>>(items, iq8, iscal, meanb);
    } else {
        mean_kernel_f32<<<dim3(B_), dim3(256), 0, stream>>>(items, item_embed, meanb);
    }
    gemm1_mfma<<<dim3(1024), dim3(256), 0, stream>>>(meanb, W1T, b1, hb);
    gemm2_mfma<<<dim3(1024), dim3(256), 0, stream>>>(hb, W2T, b2, out4, uh);
    score_mfma<<<dim3(1024), dim3(256), 0, stream>>>(uh, ch, cnormf, pminS);
    finalize_user<<<dim3(B_), dim3(256), 0, stream>>>(pminS, out4, cb, out0, diffacc);
    gather_pn<<<dim3(B_), dim3(128), 0, stream>>>(pos, neg, item_embed, out1, out2);
    diff_final<<<dim3(1), dim3(64), 0, stream>>>(diffacc, out3);
}